// Round 17
// baseline (3869.607 us; speedup 1.0000x reference)
//
#include <hip/hip_runtime.h>
#include <hip/hip_bf16.h>
#include <math.h>

#define EPSF 1e-7f
#define MAXNRM 0.99999f

static constexpr int Bb = 16, Ss = 128, Hh = 512, Vv = 10000, Ll = 3;
static constexpr int Nn = Bb * Ss; // 2048
static constexpr int VT = 625;     // vocab tiles of 16

typedef __attribute__((ext_vector_type(4))) float f32x4;
typedef __attribute__((ext_vector_type(8))) short short8v;
typedef _Float16 h2 __attribute__((ext_vector_type(2)));

__device__ inline float4 ld4(const float* p){ return *(const float4*)p; }
__device__ inline void st4(float* p, float4 v){ *(float4*)p = v; }
__device__ inline float dot4(float4 a, float4 b){ return a.x*b.x + a.y*b.y + a.z*b.z + a.w*b.w; }
__device__ inline float sigm(float x){ return 1.f/(1.f + expf(-x)); }
__device__ inline unsigned short f2bf(float f){
  __hip_bfloat16 h = __float2bfloat16(f);
  return __builtin_bit_cast(unsigned short, h);
}
__device__ inline unsigned short f2h(float f){
  _Float16 h = (_Float16)f;
  return __builtin_bit_cast(unsigned short, h);
}
__device__ inline float rsum64f(float v){
  v+=__shfl_xor(v,32); v+=__shfl_xor(v,16); v+=__shfl_xor(v,8);
  v+=__shfl_xor(v,4);  v+=__shfl_xor(v,2);  v+=__shfl_xor(v,1); return v;
}
// e5m2 quad -> two f16 pairs -> 2 fdot2  [verified rounds 9-16]
__device__ inline float dot4_e5m2(uint u, h2 L0, h2 L1, float acc){
  uint p01 = __builtin_amdgcn_perm(u, 0u, 0x05000400u);
  uint p23 = __builtin_amdgcn_perm(u, 0u, 0x07000600u);
  acc = __builtin_amdgcn_fdot2(__builtin_bit_cast(h2,p01), L0, acc, false);
  acc = __builtin_amdgcn_fdot2(__builtin_bit_cast(h2,p23), L1, acc, false);
  return acc;
}
// LLC-coherent ops [verified rounds 4-5, 11-16]
__device__ inline void stg_scu(uint* p, uint v){
  asm volatile("global_store_dword %0, %1, off sc0 sc1" :: "v"(p), "v"(v) : "memory");
}
__device__ inline uint ldg_scu(const uint* p){
  uint r;
  asm volatile("global_load_dword %0, %1, off sc0 sc1\n\ts_waitcnt vmcnt(0)"
               : "=v"(r) : "v"(p) : "memory");
  return r;
}

// ---- unified e5m2 streaming matvec: NR k4-rows starting at row0 -> dst[prow] ----
template<int NR, int PR>
__device__ __forceinline__ void stream_e5m2_rows(const uint* __restrict__ W8m,
    const uint* src2, float (*dst)[Hh], int row0, int lane, int prow){
  const int j8 = lane*8;
  const uint* W = W8m + (size_t)row0*Hh + j8;
  float acc[8] = {0,0,0,0,0,0,0,0};
  #pragma unroll 4
  for(int i=0;i<NR;i++){
    uint4 wa = *(const uint4*)(W + (size_t)i*Hh);
    uint4 wb = *(const uint4*)(W + (size_t)i*Hh + 4);
    uint2 L = *(const uint2*)&src2[(row0+i)*2];
    h2 L0=__builtin_bit_cast(h2,L.x), L1=__builtin_bit_cast(h2,L.y);
    acc[0]=dot4_e5m2(wa.x,L0,L1,acc[0]); acc[1]=dot4_e5m2(wa.y,L0,L1,acc[1]);
    acc[2]=dot4_e5m2(wa.z,L0,L1,acc[2]); acc[3]=dot4_e5m2(wa.w,L0,L1,acc[3]);
    acc[4]=dot4_e5m2(wb.x,L0,L1,acc[4]); acc[5]=dot4_e5m2(wb.y,L0,L1,acc[5]);
    acc[6]=dot4_e5m2(wb.z,L0,L1,acc[6]); acc[7]=dot4_e5m2(wb.w,L0,L1,acc[7]);
  }
  float* d = &dst[prow][j8];
  *(f32x4*)d = (f32x4){acc[0],acc[1],acc[2],acc[3]};
  *(f32x4*)(d+4) = (f32x4){acc[4],acc[5],acc[6],acc[7]};
}
// producer 8-way pair variant (1024 threads; hf selects matrix) [verified]
__device__ __forceinline__ void stream_e5m2_pair(const uint* __restrict__ WA,
    const uint* __restrict__ WB, const uint* src2, float (*part)[Hh], int tid, int j8){
  int hf = tid >> 9;
  int kq = (tid >> 6) & 7;
  const uint* W = (hf ? WB : WA) + (size_t)(kq*16)*Hh + j8;
  float acc[8] = {0,0,0,0,0,0,0,0};
  #pragma unroll 4
  for(int i=0;i<16;i++){
    uint4 wa = *(const uint4*)(W + (size_t)i*Hh);
    uint4 wb = *(const uint4*)(W + (size_t)i*Hh + 4);
    uint2 L = *(const uint2*)&src2[(kq*16+i)*2];
    h2 L0=__builtin_bit_cast(h2,L.x), L1=__builtin_bit_cast(h2,L.y);
    acc[0]=dot4_e5m2(wa.x,L0,L1,acc[0]); acc[1]=dot4_e5m2(wa.y,L0,L1,acc[1]);
    acc[2]=dot4_e5m2(wa.z,L0,L1,acc[2]); acc[3]=dot4_e5m2(wa.w,L0,L1,acc[3]);
    acc[4]=dot4_e5m2(wb.x,L0,L1,acc[4]); acc[5]=dot4_e5m2(wb.y,L0,L1,acc[5]);
    acc[6]=dot4_e5m2(wb.z,L0,L1,acc[6]); acc[7]=dot4_e5m2(wb.w,L0,L1,acc[7]);
  }
  float* d = &part[hf*8+kq][j8];
  *(f32x4*)d = (f32x4){acc[0],acc[1],acc[2],acc[3]};
  *(f32x4*)(d+4) = (f32x4){acc[4],acc[5],acc[6],acc[7]};
}

// ---------------- pack two [j][k] f32 mats -> e5m2 quads [k4][j] ----------------
__global__ __launch_bounds__(256) void k_packW8(const float* __restrict__ Wr,
    const float* __restrict__ Wz, uint* __restrict__ W8){
  int jt = blockIdx.x, kt = blockIdx.y, lm = blockIdx.z;
  int l = lm>>1, m = lm&1;
  const float* src = (m==0?Wr:Wz) + (size_t)l*Hh*Hh;
  uint* dst = W8 + (size_t)lm*(128*Hh);
  __shared__ float t[64][65];
  int tid = threadIdx.x;
  #pragma unroll
  for(int p=0;p<4;p++){
    int row = p*16 + (tid>>4);
    int c4 = (tid&15)*4;
    st4(&t[row][c4], ld4(src + ((size_t)(jt*64+row))*Hh + kt*64 + c4));
  }
  __syncthreads();
  #pragma unroll
  for(int p=0;p<4;p++){
    int k4l = p*4 + (tid>>6);
    int j_l = tid & 63;
    uint u = 0;
    #pragma unroll
    for(int i=0;i<4;i++){
      ushort b16 = __builtin_bit_cast(ushort, (_Float16)t[j_l][k4l*4+i]);
      uint b8 = (uint)((ushort)(b16 + 0x80) >> 8);
      u |= b8 << (8*i);
    }
    dst[(size_t)(kt*16 + k4l)*Hh + jt*64 + j_l] = u;
  }
}
// single-matrix variant (Wh / Uh, 3 layers)
__global__ __launch_bounds__(256) void k_packW8s(const float* __restrict__ W, uint* __restrict__ W8){
  int jt = blockIdx.x, kt = blockIdx.y, l = blockIdx.z;
  const float* src = W + (size_t)l*Hh*Hh;
  uint* dst = W8 + (size_t)l*(128*Hh);
  __shared__ float t[64][65];
  int tid = threadIdx.x;
  #pragma unroll
  for(int p=0;p<4;p++){
    int row = p*16 + (tid>>4);
    int c4 = (tid&15)*4;
    st4(&t[row][c4], ld4(src + ((size_t)(jt*64+row))*Hh + kt*64 + c4));
  }
  __syncthreads();
  #pragma unroll
  for(int p=0;p<4;p++){
    int k4l = p*4 + (tid>>6);
    int j_l = tid & 63;
    uint u = 0;
    #pragma unroll
    for(int i=0;i<4;i++){
      ushort b16 = __builtin_bit_cast(ushort, (_Float16)t[j_l][k4l*4+i]);
      uint b8 = (uint)((ushort)(b16 + 0x80) >> 8);
      u |= b8 << (8*i);
    }
    dst[(size_t)(kt*16 + k4l)*Hh + jt*64 + j_l] = u;
  }
}

// ---------------- per-(t,b) input-only dots (layer 0 only) ----------------
__global__ void k_predots(const float* __restrict__ XR, const float* __restrict__ XZ,
                          const float* __restrict__ XH,
                          const float* __restrict__ br, const float* __restrict__ bz,
                          const float* __restrict__ bh, float* __restrict__ pubX){
  int n = blockIdx.x; int tid = threadIdx.x;
  float s0=0,s1=0,s2=0,s3=0,s4=0,s5=0;
  for(int i=tid;i<Hh;i+=128){
    float xr=XR[(size_t)n*Hh+i], xz=XZ[(size_t)n*Hh+i], xh=XH[(size_t)n*Hh+i];
    s0+=xr*xr; s1+=xr*br[i]; s2+=xz*xz; s3+=xz*bz[i]; s4+=xh*xh; s5+=xh*bh[i];
  }
  __shared__ float red[2][6];
  s0=rsum64f(s0); s1=rsum64f(s1); s2=rsum64f(s2);
  s3=rsum64f(s3); s4=rsum64f(s4); s5=rsum64f(s5);
  int w = tid>>6;
  if((tid&63)==0){ red[w][0]=s0; red[w][1]=s1; red[w][2]=s2; red[w][3]=s3; red[w][4]=s4; red[w][5]=s5; }
  __syncthreads();
  if(tid==0){
    #pragma unroll
    for(int d=0;d<6;d++) pubX[(size_t)n*6+d] = red[0][d]+red[1][d];
  }
}

// ---------------- per-vocab constants ----------------
__global__ void k_pav(const float* __restrict__ P, const float* __restrict__ A,
                      float* __restrict__ pp, float* __restrict__ aa, float* __restrict__ pa){
  int w = threadIdx.x >> 6, lane = threadIdx.x & 63;
  int v = blockIdx.x*4 + w;
  const float4* Pr = (const float4*)(P + (size_t)v*Hh);
  const float4* Ar = (const float4*)(A + (size_t)v*Hh);
  float sp=0, sa=0, spa=0;
  #pragma unroll
  for(int i=0;i<2;i++){
    int k4 = lane*2 + i;
    float4 pv = Pr[k4], av = Ar[k4];
    sp += dot4(pv,pv); sa += dot4(av,av); spa += dot4(pv,av);
  }
  for(int o=32;o;o>>=1){ sp+=__shfl_down(sp,o); sa+=__shfl_down(sa,o); spa+=__shfl_down(spa,o); }
  if(lane==0){ pp[v]=sp; aa[v]=sqrtf(sa+EPSF); pa[v]=spa; }
}

// ---------------- embedding gather ----------------
__global__ void k_embed(const int* __restrict__ inp, const float* __restrict__ E, float* __restrict__ X){
  int n = blockIdx.x; int t = n >> 4, b = n & 15;
  int tok = inp[b*Ss + t];
  int i = threadIdx.x;
  st4(X + (size_t)n*Hh + i*4, ld4(E + (size_t)tok*Hh + i*4));
}

// ---------------- row logmap0 ----------------
__global__ void k_logmap(const float* __restrict__ X, float* __restrict__ LX){
  int n = blockIdx.x; int t = threadIdx.x;
  __shared__ float sred[2];
  float4 v = ld4(X + (size_t)n*Hh + t*4);
  float ss = dot4(v,v);
  for(int o=32;o;o>>=1) ss += __shfl_down(ss,o);
  if((t&63)==0) sred[t>>6] = ss;
  __syncthreads();
  ss = sred[0]+sred[1];
  float nn = sqrtf(ss + EPSF);
  float sc = atanhf(fminf(nn, MAXNRM)) / nn;
  v.x*=sc; v.y*=sc; v.z*=sc; v.w*=sc;
  st4(LX + (size_t)n*Hh + t*4, v);
}

// ---------------- row expmap0 (in place, 3 buffers) ----------------
__global__ void k_expmap(float* __restrict__ XR, float* __restrict__ XZ, float* __restrict__ XH){
  float* Xp = blockIdx.y==0 ? XR : (blockIdx.y==1 ? XZ : XH);
  int n = blockIdx.x; int t = threadIdx.x;
  __shared__ float sred[2];
  float4 v = ld4(Xp + (size_t)n*Hh + t*4);
  float ss = dot4(v,v);
  for(int o=32;o;o>>=1) ss += __shfl_down(ss,o);
  if((t&63)==0) sred[t>>6] = ss;
  __syncthreads();
  ss = sred[0]+sred[1];
  float nn = sqrtf(ss + EPSF);
  float sc = tanhf(nn) / nn;
  v.x*=sc; v.y*=sc; v.z*=sc; v.w*=sc;
  st4(Xp + (size_t)n*Hh + t*4, v);
}

// ---------------- GEMM for layer-0 inputs ----------------
__global__ __launch_bounds__(256) void k_gemm(const float* __restrict__ A4,
    const float* __restrict__ U0, const float* __restrict__ U1, const float* __restrict__ U2,
    float* __restrict__ O0, float* __restrict__ O1, float* __restrict__ O2){
  __shared__ float As[16][65], Bs[16][65];
  int jb = blockIdx.x;
  int nb = blockIdx.y;
  int mat = jb >> 3; int j0 = (jb & 7)*64;
  const float* Bm = mat==0?U0 : (mat==1?U1:U2);
  float* Om       = mat==0?O0 : (mat==1?O1:O2);
  int tid = threadIdx.x;
  int lr = tid >> 2, lq = tid & 3;
  int tx = tid & 15, ty = tid >> 4;
  float acc[4][4] = {};
  for(int kb=0; kb<Hh; kb+=16){
    float4 av = ld4(A4 + (size_t)(nb*64+lr)*Hh + kb + lq*4);
    float4 bv = ld4(Bm + (size_t)(j0+lr)*Hh + kb + lq*4);
    As[lq*4+0][lr]=av.x; As[lq*4+1][lr]=av.y; As[lq*4+2][lr]=av.z; As[lq*4+3][lr]=av.w;
    Bs[lq*4+0][lr]=bv.x; Bs[lq*4+1][lr]=bv.y; Bs[lq*4+2][lr]=bv.z; Bs[lq*4+3][lr]=bv.w;
    __syncthreads();
    #pragma unroll
    for(int kk=0;kk<16;kk++){
      float a0=As[kk][ty*4+0], a1=As[kk][ty*4+1], a2=As[kk][ty*4+2], a3=As[kk][ty*4+3];
      float b0=Bs[kk][tx*4+0], b1=Bs[kk][tx*4+1], b2=Bs[kk][tx*4+2], b3=Bs[kk][tx*4+3];
      acc[0][0]+=a0*b0; acc[0][1]+=a0*b1; acc[0][2]+=a0*b2; acc[0][3]+=a0*b3;
      acc[1][0]+=a1*b0; acc[1][1]+=a1*b1; acc[1][2]+=a1*b2; acc[1][3]+=a1*b3;
      acc[2][0]+=a2*b0; acc[2][1]+=a2*b1; acc[2][2]+=a2*b2; acc[2][3]+=a2*b3;
      acc[3][0]+=a3*b0; acc[3][1]+=a3*b1; acc[3][2]+=a3*b2; acc[3][3]+=a3*b3;
    }
    __syncthreads();
  }
  for(int i=0;i<4;i++)
    for(int j2=0;j2<4;j2++)
      Om[(size_t)(nb*64+ty*4+i)*Hh + j0 + tx*4 + j2] = acc[i][j2];
}

// ---------------- fused 3-layer pipelined GRU scan: split-B-dots consumer ----------------
__global__ __launch_bounds__(1024) void k_mega(
    const float* __restrict__ XR, const float* __restrict__ XZ, const float* __restrict__ XH,
    const float* __restrict__ pubX,
    const uint* __restrict__ W8, const uint* __restrict__ W8h,
    const uint* __restrict__ U8, const uint* __restrict__ U8h,
    const float* __restrict__ brA, const float* __restrict__ bzA, const float* __restrict__ bhA,
    uint* __restrict__ LH0, uint* __restrict__ LH1,
    int* __restrict__ flags0, int* __restrict__ flags1,
    float* __restrict__ Xfin){
  const int xcd = blockIdx.x & 7;
  const int layer = xcd >> 1;
  if(layer >= 3) return;
  const int b = (xcd & 1)*8 + (blockIdx.x >> 3);
  const int tid = threadIdx.x;
  const int lane = tid & 63, wv = tid >> 6;
  const int j8 = lane * 8;

  const uint* W8r = W8 + (size_t)(layer*2+0)*128*Hh;
  const uint* W8z = W8 + (size_t)(layer*2+1)*128*Hh;
  const uint* Wh8 = W8h + (size_t)layer*128*Hh;
  const uint* U8r = U8 + (size_t)(layer*2+0)*128*Hh;
  const uint* U8z = U8 + (size_t)(layer*2+1)*128*Hh;
  const uint* Uh8 = U8h + (size_t)layer*128*Hh;
  const float* br = brA + layer*Hh;
  const float* bz = bzA + layer*Hh;
  const float* bh = bhA + layer*Hh;
  uint* outLH = (layer==0)? LH0 : (layer==1)? LH1 : nullptr;
  int* outF = (layer==0)? flags0 : (layer==1)? flags1 : nullptr;
  const uint* inLH = (layer==1)? LH0 : LH1;
  int* inF = (layer==1)? flags0 : flags1;

  __shared__ float part[16][Hh];     // 32KB
  __shared__ float partC[8][Hh];     // 16KB (consumer Uh partials)
  __shared__ float mr_s[Hh], mur_s[Hh];
  __shared__ float h_s[Hh], mz_s[Hh], muz_s[Hh];   // mirrors for split B-dots
  __shared__ uint  lh2_s[256], ap2_s[256], lx2_s[256];
  __shared__ float bias0[Hh], bias1[Hh], bias2[Hh];
  __shared__ float partA[8][16];
  __shared__ float partB[8][18];
  __shared__ float coefA_s[12], coefB_s[8], bb_s[4];

  if(tid<256) lh2_s[tid]=0u;
  if(tid<512) h_s[tid]=0.f;
  for(int i=tid;i<Hh;i+=1024){ bias0[i]=br[i]; bias1[i]=bz[i]; bias2[i]=bh[i]; }
  __syncthreads();
  {
    float p0=0,p1=0,p2=0;
    if(tid<Hh){ float a=bias0[tid],b2=bias1[tid],c2=bias2[tid]; p0=a*a; p1=b2*b2; p2=c2*c2; }
    p0=rsum64f(p0); p1=rsum64f(p1); p2=rsum64f(p2);
    if(tid<Hh && lane==0){ partB[wv][0]=p0; partB[wv][1]=p1; partB[wv][2]=p2; }
    __syncthreads();
    if(tid==0){
      float a=0,b2=0,c2=0;
      for(int i=0;i<8;i++){ a+=partB[i][0]; b2+=partB[i][1]; c2+=partB[i][2]; }
      bb_s[0]=a; bb_s[1]=b2; bb_s[2]=c2;
    }
    __syncthreads();
  }

  float h = 0.f;
  float Sh = 0.f, hxh = 0.f, hbh = 0.f;   // tid 0 (producer path)

  for(int ts=0; ts<Ss; ts++){
    const size_t row = (size_t)(ts*Bb + b)*Hh;
    const size_t lrow = (size_t)(ts*Bb + b)*256;

    if(layer == 0){
      // ======== producer (layer 0): verified body ========
      float xr=0,xz=0,xh=0;
      if(tid<512){ xr=XR[row+tid]; xz=XZ[row+tid]; xh=XH[row+tid]; }
      stream_e5m2_pair(W8r, W8z, lh2_s, part, tid, j8);
      __syncthreads();
      float mr=0.f, mz=0.f;
      if(tid<512){
        float s0=0, s1=0;
        #pragma unroll
        for(int q=0;q<8;q++){ s0+=part[q][tid]; s1+=part[8+q][tid]; }
        mr=s0; mz=s1; mr_s[tid]=s0;
        float brc=bias0[tid], bzc=bias1[tid], bhc=bias2[tid];
        float p0=mr*mr, p1=mr*xr, p2=mr*brc, p3=mz*mz, p4=mz*xz, p5=mz*bzc, p6=h*xh, p7=h*bhc;
        p0=rsum64f(p0); p1=rsum64f(p1); p2=rsum64f(p2); p3=rsum64f(p3);
        p4=rsum64f(p4); p5=rsum64f(p5); p6=rsum64f(p6); p7=rsum64f(p7);
        if(lane==0){
          partA[wv][0]=p0; partA[wv][1]=p1; partA[wv][2]=p2; partA[wv][3]=p3;
          partA[wv][4]=p4; partA[wv][5]=p5; partA[wv][6]=p6; partA[wv][7]=p7;
        }
      }
      __syncthreads();
      if(tid==0){
        float s[8];
        #pragma unroll
        for(int d=0;d<8;d++){
          float x=0;
          for(int i=0;i<8;i++) x+=partA[i][d];
          s[d]=x;
        }
        hxh=s[6]; hbh=s[7];
        const float* px = pubX + (size_t)(ts*Bb+b)*6;
        float xrxr=px[0], xrbr=px[1], xzxz=px[2], xzbz=px[3];
        float bbr=bb_s[0], bbz=bb_s[1];
        float nm=sqrtf(s[0]+EPSF), se=tanhf(nm)/nm;
        float uv=se*s[1], uu=se*se*s[0];
        float den=1.f+2.f*uv+uu*xrxr;
        float a1=(1.f+2.f*uv+xrxr)*se/den, a2=(1.f-uu)/den;
        float uv2=a1*s[2]+a2*xrbr;
        float uu2=a1*a1*s[0]+2.f*a1*a2*s[1]+a2*a2*xrxr;
        float den2=1.f+2.f*uv2+uu2*bbr;
        float b1=(1.f+2.f*uv2+bbr)/den2, b2c=(1.f-uu2)/den2;
        float c1=b1*a1, c2=b1*a2, c3=b2c;
        float n2sq=c1*c1*s[0]+c2*c2*xrxr+c3*c3*bbr+2.f*(c1*c2*s[1]+c1*c3*s[2]+c2*c3*xrbr);
        float nn2=sqrtf(n2sq+EPSF);
        float s_r=atanhf(fminf(nn2,MAXNRM))/nn2;
        coefA_s[0]=s_r*c1; coefA_s[1]=s_r*c2; coefA_s[2]=s_r*c3;
        float nmz=sqrtf(s[3]+EPSF), sez=tanhf(nmz)/nmz;
        float uvz=sez*s[4], uuz=sez*sez*s[3];
        float denz=1.f+2.f*uvz+uuz*xzxz;
        float az1=(1.f+2.f*uvz+xzxz)*sez/denz, az2=(1.f-uuz)/denz;
        float uvz2=az1*s[5]+az2*xzbz;
        float uuz2=az1*az1*s[3]+2.f*az1*az2*s[4]+az2*az2*xzxz;
        float denz2=1.f+2.f*uvz2+uuz2*bbz;
        float bz1=(1.f+2.f*uvz2+bbz)/denz2, bz2=(1.f-uuz2)/denz2;
        float cz1=bz1*az1, cz2=bz1*az2, cz3=bz2;
        float nz2sq=cz1*cz1*s[3]+cz2*cz2*xzxz+cz3*cz3*bbz+2.f*(cz1*cz2*s[4]+cz1*cz3*s[5]+cz2*cz3*xzbz);
        float nnz2=sqrtf(nz2sq+EPSF);
        float s_z=atanhf(fminf(nnz2,MAXNRM))/nnz2;
        coefA_s[3]=s_z*cz1; coefA_s[4]=s_z*cz2; coefA_s[5]=s_z*cz3;
        coefA_s[6]=px[4]; coefA_s[7]=px[4]; coefA_s[8]=px[5];
      }
      __syncthreads();
      if(tid<256){
        int e0 = tid*2;
        float ca=coefA_s[0], cb=coefA_s[1], cc2=coefA_s[2];
        h2 lp = __builtin_bit_cast(h2, lh2_s[tid]);
        float r0 = sigm(ca*mr_s[e0]   + cb*XR[row+e0]   + cc2*bias0[e0]);
        float r1 = sigm(ca*mr_s[e0+1] + cb*XR[row+e0+1] + cc2*bias0[e0+1]);
        ap2_s[tid] = (uint)f2h(r0*(float)lp[0]) | ((uint)f2h(r1*(float)lp[1])<<16);
      }
      __syncthreads();
      stream_e5m2_rows<8,16>(Wh8, ap2_s, part, (tid>>6)*8, lane, tid>>6);
      __syncthreads();
      float mh=0.f, z=0.f;
      if(tid<512){
        float s=0;
        #pragma unroll
        for(int q=0;q<16;q++) s+=part[q][tid];
        mh=s;
        float bhc=bias2[tid], bzc=bias1[tid];
        z = sigm(coefA_s[3]*mz + coefA_s[4]*xz + coefA_s[5]*bzc);
        float eh=z*h, em=z*mh, ex=z*xh, eb=z*bhc;
        float p[18] = {mh*mh, mh*xh, mh*bhc, h*mh,
                       eh*eh, eh*em, eh*ex, eh*eb,
                       em*em, em*ex, em*eb, ex*ex, ex*eb, eb*eb,
                       h*eh, h*em, h*ex, h*eb};
        #pragma unroll
        for(int d=0;d<18;d++) p[d]=rsum64f(p[d]);
        if(lane==0){
          #pragma unroll
          for(int d=0;d<18;d++) partB[wv][d]=p[d];
        }
      }
      __syncthreads();
      if(tid==0){
        float dsum[18];
        #pragma unroll
        for(int d=0;d<18;d++){
          float x=0;
          for(int i=0;i<8;i++) x+=partB[i][d];
          dsum[d]=x;
        }
        float d0=dsum[0], d1=dsum[1], d2=dsum[2], d3=dsum[3];
        float Ghh=dsum[4], Ghm=dsum[5], Ghx=dsum[6], Ghb=dsum[7];
        float Gmm=dsum[8], Gmx=dsum[9], Gmb=dsum[10];
        float Gxx=dsum[11], Gxb=dsum[12], Gbb=dsum[13];
        float Heh=dsum[14], Hem=dsum[15], Hex=dsum[16], Heb=dsum[17];
        float xhxh=coefA_s[7], xhbh=coefA_s[8];
        float bbh=bb_s[2]; float Shb=Sh;
        float nm3=sqrtf(d0+EPSF), se3=tanhf(nm3)/nm3;
        float uvh=se3*d1, uuh=se3*se3*d0;
        float denh=1.f+2.f*uvh+uuh*xhxh;
        float a1p=(1.f+2.f*uvh+xhxh)*se3/denh, a2p=(1.f-uuh)/denh;
        float uv2h=a1p*d2+a2p*xhbh;
        float uu2h=a1p*a1p*d0+2.f*a1p*a2p*d1+a2p*a2p*xhxh;
        float den2h=1.f+2.f*uv2h+uu2h*bbh;
        float b1p=(1.f+2.f*uv2h+bbh)/den2h, b2p=(1.f-uu2h)/den2h;
        float c1p=b1p*a1p, c2p=b1p*a2p, c3p=b2p;
        float h_htil=c1p*d3+c2p*hxh+c3p*hbh;
        float htil2=c1p*c1p*d0+c2p*c2p*xhxh+c3p*c3p*bbh
                  +2.f*(c1p*c2p*d1+c1p*c3p*d2+c2p*c3p*xhbh);
        float denD=1.f-2.f*h_htil+Shb*htil2;
        float dd1=(1.f-2.f*h_htil+htil2)/denD, dd2=(1.f-Shb)/denD;
        float g0=-dd1, g1=dd2*c1p, g2=dd2*c2p, g3=dd2*c3p;
        float del2=g0*g0*Shb+g1*g1*d0+g2*g2*xhxh+g3*g3*bbh
                 +2.f*(g0*g1*d3+g0*g2*hxh+g0*g3*hbh+g1*g2*d1+g1*g3*d2+g2*g3*xhbh);
        float ndl=sqrtf(del2+EPSF);
        float sld=atanhf(fminf(ndl,MAXNRM))/ndl;
        float Qe=g0*g0*Ghh+g1*g1*Gmm+g2*g2*Gxx+g3*g3*Gbb
               +2.f*(g0*g1*Ghm+g0*g2*Ghx+g0*g3*Ghb+g1*g2*Gmx+g1*g3*Gmb+g2*g3*Gxb);
        float Le=g0*Heh+g1*Hem+g2*Hex+g3*Heb;
        float Sww=sld*sld*Qe;
        float Shw=sld*Le;
        float nw=sqrtf(Sww+EPSF), sew=tanhf(nw)/nw;
        float uvw=sew*Shw, vvw=sew*sew*Sww;
        float denw=1.f+2.f*uvw+Shb*vvw;
        float q1=(1.f+2.f*uvw+vvw)/denw, q2=((1.f-Shb)/denw)*sew;
        float n2h=q1*q1*Shb+2.f*q1*q2*Shw+q2*q2*Sww;
        float nrm=sqrtf(n2h+EPSF);
        float scl=fminf(1.f, MAXNRM/nrm);
        float Shn=scl*scl*n2h;
        float nh2=sqrtf(Shn+EPSF);
        float slh=atanhf(fminf(nh2,MAXNRM))/nh2;
        coefB_s[0]=scl*q1; coefB_s[1]=scl*q2*sld;
        coefB_s[2]=g0; coefB_s[3]=g1; coefB_s[4]=g2; coefB_s[5]=g3;
        coefB_s[6]=slh;
        Sh=Shn;
      }
      __syncthreads();
      if(tid<512){
        float qc1=coefB_s[0], qc2=coefB_s[1];
        float g0=coefB_s[2], g1=coefB_s[3], g2=coefB_s[4], g3=coefB_s[5];
        float slh=coefB_s[6];
        float dl = g0*h + g1*mh + g2*xh + g3*bias2[tid];
        float hn = qc1*h + qc2*z*dl;
        h = hn;
        float lh = slh*hn;
        float lhp = __shfl_xor(lh, 1);
        if(!(tid&1)){
          uint pk = (uint)f2h(lh) | ((uint)f2h(lhp)<<16);
          lh2_s[tid>>1] = pk;
          stg_scu(outLH + lrow + (tid>>1), pk);
        }
      }
      __syncthreads();
      if(tid==0) __hip_atomic_store(outF + b*Ss + ts, 1, __ATOMIC_RELAXED, __HIP_MEMORY_SCOPE_AGENT);
    } else {
      // ======== consumer (layers 1,2): merged streams + chain overlap + split B-dots ========
      // P1: A-half streams W8r/W8z | B-half: flag-spin + own-range lx load + U8r/U8z streams
      if(tid < 512){
        if(wv < 4) stream_e5m2_rows<32,16>(W8r, lh2_s, part, wv*32, lane, wv);
        else       stream_e5m2_rows<32,16>(W8z, lh2_s, part, (wv-4)*32, lane, wv);
      } else {
        int uw = wv - 8;
        int rbase = (uw & 3) * 32;
        if(lane==0){
          while(__hip_atomic_load(inF + b*Ss + ts, __ATOMIC_RELAXED, __HIP_MEMORY_SCOPE_AGENT) == 0)
            __builtin_amdgcn_s_sleep(1);
        }
        lx2_s[rbase*2 + lane] = ldg_scu(inLH + lrow + rbase*2 + lane);
        if(uw < 4) stream_e5m2_rows<32,16>(U8r, lx2_s, part, rbase, lane, wv);
        else       stream_e5m2_rows<32,16>(U8z, lx2_s, part, rbase, lane, wv);
      }
      __syncthreads();   // B1

      // P2: A-half: ALL m reductions + 10 gate dots (+ mz/muz mirrors) | B-half: Uh stream
      float mr=0.f, mz=0.f, mur=0.f, muz=0.f;
      if(tid < 512){
        mr  = part[0][tid]+part[1][tid]+part[2][tid]+part[3][tid];
        mz  = part[4][tid]+part[5][tid]+part[6][tid]+part[7][tid];
        mur = part[8][tid]+part[9][tid]+part[10][tid]+part[11][tid];
        muz = part[12][tid]+part[13][tid]+part[14][tid]+part[15][tid];
        mr_s[tid]=mr; mur_s[tid]=mur; mz_s[tid]=mz; muz_s[tid]=muz;
        float brc=bias0[tid], bzc=bias1[tid];
        float p0=mr*mr, p1=mr*brc, p2=mz*mz, p3=mz*bzc;
        float p5=mur*mur, p6=mur*brc, p7=muz*muz, p8=muz*bzc, p9=mr*mur, p10=mz*muz;
        p0=rsum64f(p0); p1=rsum64f(p1); p2=rsum64f(p2); p3=rsum64f(p3);
        p5=rsum64f(p5); p6=rsum64f(p6); p7=rsum64f(p7);
        p8=rsum64f(p8); p9=rsum64f(p9); p10=rsum64f(p10);
        if(lane==0){
          partA[wv][0]=p0; partA[wv][1]=p1; partA[wv][2]=p2; partA[wv][3]=p3;
          partA[wv][5]=p5; partA[wv][6]=p6; partA[wv][7]=p7;
          partA[wv][8]=p8; partA[wv][9]=p9; partA[wv][10]=p10;
        }
      } else {
        stream_e5m2_rows<16,8>(Uh8, lx2_s, partC, (wv-8)*16, lane, wv-8);
      }
      __syncthreads();   // B2

      // P3: A-half: muh reduce + h-dots | tid512: r/z gate chains
      float muh=0.f;
      if(tid<512){
        float s=0;
        #pragma unroll
        for(int q=0;q<8;q++) s+=partC[q][tid];
        muh=s;
        float bhc=bias2[tid];
        float p11=muh*muh, p12=h*muh, p13=muh*bhc, p14=h*bhc;
        p11=rsum64f(p11); p12=rsum64f(p12); p13=rsum64f(p13); p14=rsum64f(p14);
        if(lane==0){ partA[wv][11]=p11; partA[wv][12]=p12; partA[wv][13]=p13; partA[wv][14]=p14; }
      } else if(tid==512){
        float S[11];
        #pragma unroll
        for(int d=0;d<11;d++){
          float xS=0;
          for(int i=0;i<8;i++) xS+=partA[i][d];
          S[d]=xS;
        }
        float bbr=bb_s[0], bbz=bb_s[1];
        float nur=sqrtf(S[5]+EPSF), se_r=tanhf(nur)/nur;
        float nuz=sqrtf(S[7]+EPSF), se_z=tanhf(nuz)/nuz;
        float s0=S[0], s1=se_r*S[9], s2=S[1];
        float xrxr=se_r*se_r*S[5], xrbr=se_r*S[6];
        float s3=S[2], s4=se_z*S[10], s5=S[3];
        float xzxz=se_z*se_z*S[7], xzbz=se_z*S[8];
        float nm=sqrtf(s0+EPSF), se=tanhf(nm)/nm;
        float uv=se*s1, uu=se*se*s0;
        float den=1.f+2.f*uv+uu*xrxr;
        float a1=(1.f+2.f*uv+xrxr)*se/den, a2=(1.f-uu)/den;
        float uv2=a1*s2+a2*xrbr;
        float uu2=a1*a1*s0+2.f*a1*a2*s1+a2*a2*xrxr;
        float den2=1.f+2.f*uv2+uu2*bbr;
        float b1=(1.f+2.f*uv2+bbr)/den2, b2c=(1.f-uu2)/den2;
        float c1=b1*a1, c2=b1*a2, c3=b2c;
        float n2sq=c1*c1*s0+c2*c2*xrxr+c3*c3*bbr+2.f*(c1*c2*s1+c1*c3*s2+c2*c3*xrbr);
        float nn2=sqrtf(n2sq+EPSF);
        float s_r=atanhf(fminf(nn2,MAXNRM))/nn2;
        coefA_s[0]=s_r*c1; coefA_s[1]=s_r*c2*se_r; coefA_s[2]=s_r*c3;
        float nmz=sqrtf(s3+EPSF), sez=tanhf(nmz)/nmz;
        float uvz=sez*s4, uuz=sez*sez*s3;
        float denz=1.f+2.f*uvz+uuz*xzxz;
        float az1=(1.f+2.f*uvz+xzxz)*sez/denz, az2=(1.f-uuz)/denz;
        float uvz2=az1*s5+az2*xzbz;
        float uuz2=az1*az1*s3+2.f*az1*az2*s4+az2*az2*xzxz;
        float denz2=1.f+2.f*uvz2+uuz2*bbz;
        float bz1=(1.f+2.f*uvz2+bbz)/denz2, bz2=(1.f-uuz2)/denz2;
        float cz1=bz1*az1, cz2=bz1*az2, cz3=bz2;
        float nz2sq=cz1*cz1*s3+cz2*cz2*xzxz+cz3*cz3*bbz+2.f*(cz1*cz2*s4+cz1*cz3*s5+cz2*cz3*xzbz);
        float nnz2=sqrtf(nz2sq+EPSF);
        float s_z=atanhf(fminf(nnz2,MAXNRM))/nnz2;
        coefA_s[3]=s_z*cz1; coefA_s[4]=s_z*cz2*se_z; coefA_s[5]=s_z*cz3;
      }
      __syncthreads();   // B3

      // P4: ap pack (tid<256) | tid512: fold h-scalars
      if(tid<256){
        int e0 = tid*2;
        float ca=coefA_s[0], cbp=coefA_s[1], cc2=coefA_s[2];
        h2 lp = __builtin_bit_cast(h2, lh2_s[tid]);
        float r0 = sigm(ca*mr_s[e0]   + cbp*mur_s[e0]   + cc2*bias0[e0]);
        float r1 = sigm(ca*mr_s[e0+1] + cbp*mur_s[e0+1] + cc2*bias0[e0+1]);
        ap2_s[tid] = (uint)f2h(r0*(float)lp[0]) | ((uint)f2h(r1*(float)lp[1])<<16);
      } else if(tid==512){
        float S11=0,S12=0,S13=0,S14=0;
        #pragma unroll
        for(int i=0;i<8;i++){
          S11+=partA[i][11]; S12+=partA[i][12]; S13+=partA[i][13]; S14+=partA[i][14];
        }
        float nuh=sqrtf(S11+EPSF), se_h=tanhf(nuh)/nuh;
        coefA_s[6]=se_h;
        coefA_s[7]=se_h*se_h*S11;   // xhxh
        coefA_s[8]=se_h*S13;        // xhbh
        coefA_s[9]=se_h*S12;        // hxh
        coefA_s[10]=S14;            // hbh
      }
      __syncthreads();   // B4

      // P5: Wh stream (all 1024, 16-way)
      stream_e5m2_rows<8,16>(Wh8, ap2_s, part, (tid>>6)*8, lane, tid>>6);
      __syncthreads();   // B5

      // P6: SPLIT B-dots: A-half dots 0-8 | B-half dots 9-17 (same j coverage, same order)
      float mh=0.f, z=0.f;
      if(tid<512){
        float s=0;
        #pragma unroll
        for(int q=0;q<16;q++) s+=part[q][tid];
        mh=s;
        float se_h = coefA_s[6];
        float xh = se_h*muh;
        float bhc=bias2[tid], bzc=bias1[tid];
        z = sigm(coefA_s[3]*mz + coefA_s[4]*muz + coefA_s[5]*bzc);
        float eh=z*h, em=z*mh, ex=z*xh;
        float p[9] = {mh*mh, mh*xh, mh*bhc, h*mh,
                      eh*eh, eh*em, eh*ex, eh*(z*bhc), em*em};
        #pragma unroll
        for(int d=0;d<9;d++) p[d]=rsum64f(p[d]);
        if(lane==0){
          #pragma unroll
          for(int d=0;d<9;d++) partB[wv][d]=p[d];
        }
      } else {
        int j = tid - 512;
        float s=0;
        #pragma unroll
        for(int q=0;q<16;q++) s+=part[q][j];
        float mhB=s;
        float mu=0;
        #pragma unroll
        for(int q=0;q<8;q++) mu+=partC[q][j];
        float se_h = coefA_s[6];
        float xhB = se_h*mu;
        float hB = h_s[j];
        float bhc=bias2[j], bzc=bias1[j];
        float zB = sigm(coefA_s[3]*mz_s[j] + coefA_s[4]*muz_s[j] + coefA_s[5]*bzc);
        float em=zB*mhB, ex=zB*xhB, eb=zB*bhc, eh=zB*hB;
        float p[9] = {em*ex, em*eb, ex*ex, ex*eb, eb*eb,
                      hB*eh, hB*em, hB*ex, hB*eb};
        #pragma unroll
        for(int d=0;d<9;d++) p[d]=rsum64f(p[d]);
        if(lane==0){
          #pragma unroll
          for(int d=0;d<9;d++) partB[wv-8][9+d]=p[d];
        }
      }
      __syncthreads();   // B6

      // P7: coefB (tid0); hxh/hbh from coefA_s[9..10]
      if(tid==0){
        float dsum[18];
        #pragma unroll
        for(int d=0;d<18;d++){
          float xS=0;
          for(int i=0;i<8;i++) xS+=partB[i][d];
          dsum[d]=xS;
        }
        float d0=dsum[0], d1=dsum[1], d2=dsum[2], d3=dsum[3];
        float Ghh=dsum[4], Ghm=dsum[5], Ghx=dsum[6], Ghb=dsum[7];
        float Gmm=dsum[8], Gmx=dsum[9], Gmb=dsum[10];
        float Gxx=dsum[11], Gxb=dsum[12], Gbb=dsum[13];
        float Heh=dsum[14], Hem=dsum[15], Hex=dsum[16], Heb=dsum[17];
        float xhxh=coefA_s[7], xhbh=coefA_s[8];
        float hxhv=coefA_s[9], hbhv=coefA_s[10];
        float bbh=bb_s[2]; float Shb=Sh;
        float nm3=sqrtf(d0+EPSF), se3=tanhf(nm3)/nm3;
        float uvh=se3*d1, uuh=se3*se3*d0;
        float denh=1.f+2.f*uvh+uuh*xhxh;
        float a1p=(1.f+2.f*uvh+xhxh)*se3/denh, a2p=(1.f-uuh)/denh;
        float uv2h=a1p*d2+a2p*xhbh;
        float uu2h=a1p*a1p*d0+2.f*a1p*a2p*d1+a2p*a2p*xhxh;
        float den2h=1.f+2.f*uv2h+uu2h*bbh;
        float b1p=(1.f+2.f*uv2h+bbh)/den2h, b2p=(1.f-uu2h)/den2h;
        float c1p=b1p*a1p, c2p=b1p*a2p, c3p=b2p;
        float h_htil=c1p*d3+c2p*hxhv+c3p*hbhv;
        float htil2=c1p*c1p*d0+c2p*c2p*xhxh+c3p*c3p*bbh
                  +2.f*(c1p*c2p*d1+c1p*c3p*d2+c2p*c3p*xhbh);
        float denD=1.f-2.f*h_htil+Shb*htil2;
        float dd1=(1.f-2.f*h_htil+htil2)/denD, dd2=(1.f-Shb)/denD;
        float g0=-dd1, g1=dd2*c1p, g2=dd2*c2p, g3=dd2*c3p;
        float del2=g0*g0*Shb+g1*g1*d0+g2*g2*xhxh+g3*g3*bbh
                 +2.f*(g0*g1*d3+g0*g2*hxhv+g0*g3*hbhv+g1*g2*d1+g1*g3*d2+g2*g3*xhbh);
        float ndl=sqrtf(del2+EPSF);
        float sld=atanhf(fminf(ndl,MAXNRM))/ndl;
        float Qe=g0*g0*Ghh+g1*g1*Gmm+g2*g2*Gxx+g3*g3*Gbb
               +2.f*(g0*g1*Ghm+g0*g2*Ghx+g0*g3*Ghb+g1*g2*Gmx+g1*g3*Gmb+g2*g3*Gxb);
        float Le=g0*Heh+g1*Hem+g2*Hex+g3*Heb;
        float Sww=sld*sld*Qe;
        float Shw=sld*Le;
        float nw=sqrtf(Sww+EPSF), sew=tanhf(nw)/nw;
        float uvw=sew*Shw, vvw=sew*sew*Sww;
        float denw=1.f+2.f*uvw+Shb*vvw;
        float q1=(1.f+2.f*uvw+vvw)/denw, q2=((1.f-Shb)/denw)*sew;
        float n2h=q1*q1*Shb+2.f*q1*q2*Shw+q2*q2*Sww;
        float nrm=sqrtf(n2h+EPSF);
        float scl=fminf(1.f, MAXNRM/nrm);
        float Shn=scl*scl*n2h;
        float nh2=sqrtf(Shn+EPSF);
        float slh=atanhf(fminf(nh2,MAXNRM))/nh2;
        coefB_s[0]=scl*q1; coefB_s[1]=scl*q2*sld;
        coefB_s[2]=g0; coefB_s[3]=g1; coefB_s[4]=g2; coefB_s[5]=g3;
        coefB_s[6]=slh;
        Sh=Shn;
      }
      __syncthreads();   // B7

      // P8: update + handoff/out + h_s mirror
      if(tid<512){
        float qc1=coefB_s[0], qc2=coefB_s[1];
        float g0=coefB_s[2], g1=coefB_s[3], g2=coefB_s[4], g3=coefB_s[5];
        float slh=coefB_s[6];
        float xh = coefA_s[6]*muh;
        float dl = g0*h + g1*mh + g2*xh + g3*bias2[tid];
        float hn = qc1*h + qc2*z*dl;
        h = hn;
        h_s[tid] = hn;
        if(layer==2) Xfin[row + tid] = hn;
        float lh = slh*hn;
        float lhp = __shfl_xor(lh, 1);
        if(!(tid&1)){
          uint pk = (uint)f2h(lh) | ((uint)f2h(lhp)<<16);
          lh2_s[tid>>1] = pk;
          if(layer==1) stg_scu(outLH + lrow + (tid>>1), pk);
        }
      }
      __syncthreads();   // B8
      if(layer==1 && tid==0)
        __hip_atomic_store(outF + b*Ss + ts, 1, __ATOMIC_RELAXED, __HIP_MEMORY_SCOPE_AGENT);
    }
  }
}

// ---------------- pack 16 rows of a [*,512] f32 matrix into bf16 MFMA fragments ----------------
__global__ __launch_bounds__(256) void k_packF(const float* __restrict__ src, ushort* __restrict__ dst){
  int vt = blockIdx.x;
  __shared__ float rows[16][516];
  int tid = threadIdx.x;
  #pragma unroll
  for(int p=0;p<8;p++){
    int idx = p*256 + tid;
    int row = idx >> 7, c4 = idx & 127;
    st4(&rows[row][c4*4], ld4(src + ((size_t)vt*16+row)*Hh + c4*4));
  }
  __syncthreads();
  #pragma unroll
  for(int p=0;p<4;p++){
    int idx = p*256 + tid;
    int kt = idx >> 6, lane = idx & 63;
    int vloc = lane & 15, k0 = kt*32 + ((lane>>4)&3)*8;
    union { ushort u[8]; uint4 v; } tt;
    #pragma unroll
    for(int i=0;i<8;i++) tt.u[i] = f2bf(rows[vloc][k0+i]);
    *(uint4*)(dst + (((size_t)vt*16 + kt)*64 + lane)*8) = tt.v;
  }
}

// ---------------- MFMA MLR + online softmax partials ----------------
__global__ __launch_bounds__(256) void k_mlr2(
    const ushort* __restrict__ Xf, const ushort* __restrict__ Pf, const ushort* __restrict__ Af,
    const float* __restrict__ X, const float* __restrict__ pp, const float* __restrict__ aa,
    const float* __restrict__ pa, const int* __restrict__ tgt,
    float* __restrict__ pm, float* __restrict__ tl){
  int rb = blockIdx.x;
  int sp = blockIdx.y;
  int tid = threadIdx.x, lane = tid&63, w = tid>>6;
  __shared__ ushort Axf[4*16*64*8];
  __shared__ float xxp[64][4];
  __shared__ float xxs[64];
  #pragma unroll
  for(int p=0;p<16;p++){
    int idx = p*256 + tid;
    ((uint4*)Axf)[idx] = ((const uint4*)Xf)[(size_t)rb*4096 + idx];
  }
  {
    int row = tid>>2, seg = tid&3;
    const float* xr = X + ((size_t)rb*64 + row)*Hh + seg*128;
    float s=0;
    #pragma unroll
    for(int i=0;i<32;i++){ float4 v4 = ld4(xr+i*4); s += dot4(v4,v4); }
    xxp[row][seg]=s;
  }
  __syncthreads();
  if(tid<64) xxs[tid] = xxp[tid][0]+xxp[tid][1]+xxp[tid][2]+xxp[tid][3];
  __syncthreads();

  float mM[16], sS[16]; int tokv[16];
  #pragma unroll
  for(int rt=0;rt<4;rt++)
    #pragma unroll
    for(int i=0;i<4;i++){
      int idx=rt*4+i;
      int rr = rb*64 + rt*16 + (lane>>4)*4 + i;
      tokv[idx] = tgt[(rr&15)*Ss + (rr>>4)];
      mM[idx] = -3.0e38f; sS[idx]=0.f;
    }

  for(int vt = sp*4 + w; vt < VT; vt += 32){
    int v = vt*16 + (lane&15);
    float ppv = pp[v], aav = aa[v], pav = pa[v];
    f32x4 aP[4], aA[4];
    #pragma unroll
    for(int rt=0;rt<4;rt++){ aP[rt]=(f32x4){0,0,0,0}; aA[rt]=(f32x4){0,0,0,0}; }
    const short8v* Pb = (const short8v*)(Pf + (size_t)vt*8192);
    const short8v* Ab = (const short8v*)(Af + (size_t)vt*8192);
    #pragma unroll
    for(int kt=0;kt<16;kt++){
      short8v bP = Pb[kt*64+lane];
      short8v bA = Ab[kt*64+lane];
      #pragma unroll
      for(int rt=0;rt<4;rt++){
        short8v a = *(const short8v*)&Axf[(((size_t)rt*16+kt)*64+lane)*8];
        aP[rt] = __builtin_amdgcn_mfma_f32_16x16x32_bf16(a, bP, aP[rt], 0,0,0);
        aA[rt] = __builtin_amdgcn_mfma_f32_16x16x32_bf16(a, bA, aA[rt], 0,0,0);
      }
    }
    float be = 1.f - ppv;
    float lamaa = (2.f/be)*aav;
    #pragma unroll
    for(int rt=0;rt<4;rt++)
      #pragma unroll
      for(int i=0;i<4;i++){
        int idx = rt*4+i;
        int rl = rt*16 + (lane>>4)*4 + i;
        float px = aP[rt][i], xa = aA[rt][i];
        float xx = xxs[rl];
        float al = 1.f - 2.f*px + xx;
        float gm = 1.f - 2.f*px + ppv*xx;
        float da = (-al*pav + be*xa)/gm;
        float dd = (al*al*ppv - 2.f*al*be*px + be*be*xx)/(gm*gm);
        float arg = 2.f*da/((1.f-dd)*aav + EPSF);
        float lg = lamaa*asinhf(arg);
        if(v == tokv[idx]) tl[rb*64 + rl] = lg;
        if(lg > mM[idx]){ sS[idx] = sS[idx]*expf(mM[idx]-lg) + 1.f; mM[idx]=lg; }
        else sS[idx] += expf(lg - mM[idx]);
      }
  }
  #pragma unroll
  for(int o=1;o<16;o<<=1){
    #pragma unroll
    for(int idx=0;idx<16;idx++){
      float m2 = __shfl_xor(mM[idx], o);
      float s2 = __shfl_xor(sS[idx], o);
      float M = fmaxf(mM[idx], m2);
      sS[idx] = sS[idx]*expf(mM[idx]-M) + s2*expf(m2-M);
      mM[idx] = M;
    }
  }
  if((lane&15)==0){
    #pragma unroll
    for(int rt=0;rt<4;rt++)
      #pragma unroll
      for(int i=0;i<4;i++){
        int idx=rt*4+i;
        int rr = rb*64 + rt*16 + (lane>>4)*4 + i;
        pm[((size_t)rr*32 + sp*4 + w)*2+0] = mM[idx];
        pm[((size_t)rr*32 + sp*4 + w)*2+1] = sS[idx];
      }
  }
}

// ---------------- final merge + mean NLL ----------------
__global__ void k_final(const float* __restrict__ pm, const float* __restrict__ tl, float* __restrict__ out){
  int tid = threadIdx.x;
  __shared__ float sred[4];
  float acc = 0.f;
  for(int q=0;q<8;q++){
    int rr = q*256 + tid;
    float M = -3.0e38f;
    for(int s=0;s<32;s++) M = fmaxf(M, pm[((size_t)rr*32+s)*2]);
    float Ssum = 0.f;
    for(int s=0;s<32;s++) Ssum += pm[((size_t)rr*32+s)*2+1]*expf(pm[((size_t)rr*32+s)*2]-M);
    acc += (M + logf(Ssum)) - tl[rr];
  }
  for(int o=32;o;o>>=1) acc += __shfl_down(acc,o);
  if((tid&63)==0) sred[tid>>6] = acc;
  __syncthreads();
  if(tid==0) out[0] = (sred[0]+sred[1]+sred[2]+sred[3]) / 2048.f;
}

extern "C" void kernel_launch(void* const* d_in, const int* in_sizes, int n_in,
                              void* d_out, int out_size, void* d_ws, size_t ws_size,
                              hipStream_t stream){
  const int* inp = (const int*)d_in[0];
  const int* tgt = (const int*)d_in[1];
  const float* E  = (const float*)d_in[2];
  const float* Wr = (const float*)d_in[3];
  const float* Wz = (const float*)d_in[4];
  const float* Wh = (const float*)d_in[5];
  const float* Ur = (const float*)d_in[6];
  const float* Uz = (const float*)d_in[7];
  const float* Uh = (const float*)d_in[8];
  const float* br = (const float*)d_in[9];
  const float* bz = (const float*)d_in[10];
  const float* bh = (const float*)d_in[11];
  const float* P  = (const float*)d_in[12];
  const float* A  = (const float*)d_in[13];
  float* out = (float*)d_out;
  float* w = (float*)d_ws;
  size_t o = 0;
  auto take = [&](size_t n){ float* p = w + o; o += n; return p; };
  float* Xa  = take((size_t)Nn*Hh);
  float* Xb  = take((size_t)Nn*Hh);
  float* LX  = take((size_t)Nn*Hh);
  float* XR  = take((size_t)Nn*Hh);
  float* XZ  = take((size_t)Nn*Hh);
  float* XH  = take((size_t)Nn*Hh);
  uint*  LH0 = (uint*)take((size_t)Nn*256);
  uint*  LH1 = (uint*)take((size_t)Nn*256);
  uint*  W8h = (uint*)take((size_t)3*128*Hh);
  uint*  W8  = (uint*)take((size_t)6*128*Hh);
  uint*  U8h = (uint*)take((size_t)3*128*Hh);
  uint*  U8  = (uint*)take((size_t)6*128*Hh);
  float* pubX = take((size_t)Nn*6);
  float* pp  = take(10240);
  float* aa  = take(10240);
  float* pa  = take(10240);
  float* pm  = take((size_t)Nn*32*2);
  float* tl  = take((size_t)Nn);
  int* flags = (int*)take(2*(size_t)Bb*Ss);
  if(ws_size < o*sizeof(float)) return;
  int* flags0 = flags;
  int* flags1 = flags + Bb*Ss;

  hipLaunchKernelGGL(k_packW8s, dim3(8,8,3), dim3(256), 0, stream, Wh, W8h);
  hipLaunchKernelGGL(k_packW8s, dim3(8,8,3), dim3(256), 0, stream, Uh, U8h);
  hipLaunchKernelGGL(k_packW8, dim3(8,8,6), dim3(256), 0, stream, Wr, Wz, W8);
  hipLaunchKernelGGL(k_packW8, dim3(8,8,6), dim3(256), 0, stream, Ur, Uz, U8);
  hipLaunchKernelGGL(k_pav, dim3(2500), dim3(256), 0, stream, P,A, pp,aa,pa);
  hipLaunchKernelGGL(k_embed, dim3(Nn), dim3(128), 0, stream, inp, E, Xa);
  hipLaunchKernelGGL(k_logmap, dim3(Nn), dim3(128), 0, stream, Xa, LX);
  hipLaunchKernelGGL(k_gemm, dim3(24,32), dim3(256), 0, stream, LX,
                     Ur, Uz, Uh, XR, XZ, XH);
  hipLaunchKernelGGL(k_expmap, dim3(Nn,3), dim3(128), 0, stream, XR,XZ,XH);
  hipLaunchKernelGGL(k_predots, dim3(Nn), dim3(128), 0, stream, XR,XZ,XH, br, bz, bh, pubX);
  hipMemsetAsync(flags, 0, 2*(size_t)Bb*Ss*sizeof(int), stream);
  hipLaunchKernelGGL(k_mega, dim3(64), dim3(1024), 0, stream,
                     XR,XZ,XH, pubX, W8,W8h,U8,U8h, br,bz,bh,
                     LH0, LH1, flags0, flags1, Xb);
  ushort* Pf = (ushort*)LX;
  ushort* Af = Pf + (size_t)VT*16*64*8;
  ushort* Xf = (ushort*)Xa;
  hipLaunchKernelGGL(k_packF, dim3(VT), dim3(256), 0, stream, P, Pf);
  hipLaunchKernelGGL(k_packF, dim3(VT), dim3(256), 0, stream, A, Af);
  hipLaunchKernelGGL(k_packF, dim3(128), dim3(256), 0, stream, Xb, Xf);
  hipLaunchKernelGGL(k_mlr2, dim3(32,8), dim3(256), 0, stream, Xf, Pf, Af, Xb,
                     pp, aa, pa, tgt, pm, tl);
  hipLaunchKernelGGL(k_final, dim3(1), dim3(256), 0, stream, pm, tl, out);
}

// Round 18
// 3768.682 us; speedup vs baseline: 1.0268x; 1.0268x over previous
//
#include <hip/hip_runtime.h>
#include <hip/hip_bf16.h>
#include <math.h>

#define EPSF 1e-7f
#define MAXNRM 0.99999f

static constexpr int Bb = 16, Ss = 128, Hh = 512, Vv = 10000, Ll = 3;
static constexpr int Nn = Bb * Ss; // 2048
static constexpr int VT = 625;     // vocab tiles of 16

typedef __attribute__((ext_vector_type(4))) float f32x4;
typedef __attribute__((ext_vector_type(8))) short short8v;
typedef _Float16 h2 __attribute__((ext_vector_type(2)));

__device__ inline float4 ld4(const float* p){ return *(const float4*)p; }
__device__ inline void st4(float* p, float4 v){ *(float4*)p = v; }
__device__ inline float dot4(float4 a, float4 b){ return a.x*b.x + a.y*b.y + a.z*b.z + a.w*b.w; }
__device__ inline float sigm(float x){ return 1.f/(1.f + expf(-x)); }
__device__ inline unsigned short f2bf(float f){
  __hip_bfloat16 h = __float2bfloat16(f);
  return __builtin_bit_cast(unsigned short, h);
}
__device__ inline unsigned short f2h(float f){
  _Float16 h = (_Float16)f;
  return __builtin_bit_cast(unsigned short, h);
}
__device__ inline float rsum64f(float v){
  v+=__shfl_xor(v,32); v+=__shfl_xor(v,16); v+=__shfl_xor(v,8);
  v+=__shfl_xor(v,4);  v+=__shfl_xor(v,2);  v+=__shfl_xor(v,1); return v;
}
// e5m2 quad -> two f16 pairs -> 2 fdot2  [verified rounds 9-16]
__device__ inline float dot4_e5m2(uint u, h2 L0, h2 L1, float acc){
  uint p01 = __builtin_amdgcn_perm(u, 0u, 0x05000400u);
  uint p23 = __builtin_amdgcn_perm(u, 0u, 0x07000600u);
  acc = __builtin_amdgcn_fdot2(__builtin_bit_cast(h2,p01), L0, acc, false);
  acc = __builtin_amdgcn_fdot2(__builtin_bit_cast(h2,p23), L1, acc, false);
  return acc;
}
// LLC-coherent ops [verified rounds 4-5, 11-16]
__device__ inline void stg_scu(uint* p, uint v){
  asm volatile("global_store_dword %0, %1, off sc0 sc1" :: "v"(p), "v"(v) : "memory");
}
__device__ inline uint ldg_scu(const uint* p){
  uint r;
  asm volatile("global_load_dword %0, %1, off sc0 sc1\n\ts_waitcnt vmcnt(0)"
               : "=v"(r) : "v"(p) : "memory");
  return r;
}

// ---- unified e5m2 streaming matvec: NR k4-rows starting at row0 -> dst[prow] ----
template<int NR, int PR>
__device__ __forceinline__ void stream_e5m2_rows(const uint* __restrict__ W8m,
    const uint* src2, float (*dst)[Hh], int row0, int lane, int prow){
  const int j8 = lane*8;
  const uint* W = W8m + (size_t)row0*Hh + j8;
  float acc[8] = {0,0,0,0,0,0,0,0};
  #pragma unroll 4
  for(int i=0;i<NR;i++){
    uint4 wa = *(const uint4*)(W + (size_t)i*Hh);
    uint4 wb = *(const uint4*)(W + (size_t)i*Hh + 4);
    uint2 L = *(const uint2*)&src2[(row0+i)*2];
    h2 L0=__builtin_bit_cast(h2,L.x), L1=__builtin_bit_cast(h2,L.y);
    acc[0]=dot4_e5m2(wa.x,L0,L1,acc[0]); acc[1]=dot4_e5m2(wa.y,L0,L1,acc[1]);
    acc[2]=dot4_e5m2(wa.z,L0,L1,acc[2]); acc[3]=dot4_e5m2(wa.w,L0,L1,acc[3]);
    acc[4]=dot4_e5m2(wb.x,L0,L1,acc[4]); acc[5]=dot4_e5m2(wb.y,L0,L1,acc[5]);
    acc[6]=dot4_e5m2(wb.z,L0,L1,acc[6]); acc[7]=dot4_e5m2(wb.w,L0,L1,acc[7]);
  }
  float* d = &dst[prow][j8];
  *(f32x4*)d = (f32x4){acc[0],acc[1],acc[2],acc[3]};
  *(f32x4*)(d+4) = (f32x4){acc[4],acc[5],acc[6],acc[7]};
}
// producer 8-way pair variant (1024 threads; hf selects matrix) [verified]
__device__ __forceinline__ void stream_e5m2_pair(const uint* __restrict__ WA,
    const uint* __restrict__ WB, const uint* src2, float (*part)[Hh], int tid, int j8){
  int hf = tid >> 9;
  int kq = (tid >> 6) & 7;
  const uint* W = (hf ? WB : WA) + (size_t)(kq*16)*Hh + j8;
  float acc[8] = {0,0,0,0,0,0,0,0};
  #pragma unroll 4
  for(int i=0;i<16;i++){
    uint4 wa = *(const uint4*)(W + (size_t)i*Hh);
    uint4 wb = *(const uint4*)(W + (size_t)i*Hh + 4);
    uint2 L = *(const uint2*)&src2[(kq*16+i)*2];
    h2 L0=__builtin_bit_cast(h2,L.x), L1=__builtin_bit_cast(h2,L.y);
    acc[0]=dot4_e5m2(wa.x,L0,L1,acc[0]); acc[1]=dot4_e5m2(wa.y,L0,L1,acc[1]);
    acc[2]=dot4_e5m2(wa.z,L0,L1,acc[2]); acc[3]=dot4_e5m2(wa.w,L0,L1,acc[3]);
    acc[4]=dot4_e5m2(wb.x,L0,L1,acc[4]); acc[5]=dot4_e5m2(wb.y,L0,L1,acc[5]);
    acc[6]=dot4_e5m2(wb.z,L0,L1,acc[6]); acc[7]=dot4_e5m2(wb.w,L0,L1,acc[7]);
  }
  float* d = &part[hf*8+kq][j8];
  *(f32x4*)d = (f32x4){acc[0],acc[1],acc[2],acc[3]};
  *(f32x4*)(d+4) = (f32x4){acc[4],acc[5],acc[6],acc[7]};
}

// ---------------- pack two [j][k] f32 mats -> e5m2 quads [k4][j] ----------------
__global__ __launch_bounds__(256) void k_packW8(const float* __restrict__ Wr,
    const float* __restrict__ Wz, uint* __restrict__ W8){
  int jt = blockIdx.x, kt = blockIdx.y, lm = blockIdx.z;
  int l = lm>>1, m = lm&1;
  const float* src = (m==0?Wr:Wz) + (size_t)l*Hh*Hh;
  uint* dst = W8 + (size_t)lm*(128*Hh);
  __shared__ float t[64][65];
  int tid = threadIdx.x;
  #pragma unroll
  for(int p=0;p<4;p++){
    int row = p*16 + (tid>>4);
    int c4 = (tid&15)*4;
    st4(&t[row][c4], ld4(src + ((size_t)(jt*64+row))*Hh + kt*64 + c4));
  }
  __syncthreads();
  #pragma unroll
  for(int p=0;p<4;p++){
    int k4l = p*4 + (tid>>6);
    int j_l = tid & 63;
    uint u = 0;
    #pragma unroll
    for(int i=0;i<4;i++){
      ushort b16 = __builtin_bit_cast(ushort, (_Float16)t[j_l][k4l*4+i]);
      uint b8 = (uint)((ushort)(b16 + 0x80) >> 8);
      u |= b8 << (8*i);
    }
    dst[(size_t)(kt*16 + k4l)*Hh + jt*64 + j_l] = u;
  }
}
// single-matrix variant (Wh / Uh, 3 layers)
__global__ __launch_bounds__(256) void k_packW8s(const float* __restrict__ W, uint* __restrict__ W8){
  int jt = blockIdx.x, kt = blockIdx.y, l = blockIdx.z;
  const float* src = W + (size_t)l*Hh*Hh;
  uint* dst = W8 + (size_t)l*(128*Hh);
  __shared__ float t[64][65];
  int tid = threadIdx.x;
  #pragma unroll
  for(int p=0;p<4;p++){
    int row = p*16 + (tid>>4);
    int c4 = (tid&15)*4;
    st4(&t[row][c4], ld4(src + ((size_t)(jt*64+row))*Hh + kt*64 + c4));
  }
  __syncthreads();
  #pragma unroll
  for(int p=0;p<4;p++){
    int k4l = p*4 + (tid>>6);
    int j_l = tid & 63;
    uint u = 0;
    #pragma unroll
    for(int i=0;i<4;i++){
      ushort b16 = __builtin_bit_cast(ushort, (_Float16)t[j_l][k4l*4+i]);
      uint b8 = (uint)((ushort)(b16 + 0x80) >> 8);
      u |= b8 << (8*i);
    }
    dst[(size_t)(kt*16 + k4l)*Hh + jt*64 + j_l] = u;
  }
}

// ---------------- per-(t,b) input-only dots (layer 0 only) ----------------
__global__ void k_predots(const float* __restrict__ XR, const float* __restrict__ XZ,
                          const float* __restrict__ XH,
                          const float* __restrict__ br, const float* __restrict__ bz,
                          const float* __restrict__ bh, float* __restrict__ pubX){
  int n = blockIdx.x; int tid = threadIdx.x;
  float s0=0,s1=0,s2=0,s3=0,s4=0,s5=0;
  for(int i=tid;i<Hh;i+=128){
    float xr=XR[(size_t)n*Hh+i], xz=XZ[(size_t)n*Hh+i], xh=XH[(size_t)n*Hh+i];
    s0+=xr*xr; s1+=xr*br[i]; s2+=xz*xz; s3+=xz*bz[i]; s4+=xh*xh; s5+=xh*bh[i];
  }
  __shared__ float red[2][6];
  s0=rsum64f(s0); s1=rsum64f(s1); s2=rsum64f(s2);
  s3=rsum64f(s3); s4=rsum64f(s4); s5=rsum64f(s5);
  int w = tid>>6;
  if((tid&63)==0){ red[w][0]=s0; red[w][1]=s1; red[w][2]=s2; red[w][3]=s3; red[w][4]=s4; red[w][5]=s5; }
  __syncthreads();
  if(tid==0){
    #pragma unroll
    for(int d=0;d<6;d++) pubX[(size_t)n*6+d] = red[0][d]+red[1][d];
  }
}

// ---------------- per-vocab constants ----------------
__global__ void k_pav(const float* __restrict__ P, const float* __restrict__ A,
                      float* __restrict__ pp, float* __restrict__ aa, float* __restrict__ pa){
  int w = threadIdx.x >> 6, lane = threadIdx.x & 63;
  int v = blockIdx.x*4 + w;
  const float4* Pr = (const float4*)(P + (size_t)v*Hh);
  const float4* Ar = (const float4*)(A + (size_t)v*Hh);
  float sp=0, sa=0, spa=0;
  #pragma unroll
  for(int i=0;i<2;i++){
    int k4 = lane*2 + i;
    float4 pv = Pr[k4], av = Ar[k4];
    sp += dot4(pv,pv); sa += dot4(av,av); spa += dot4(pv,av);
  }
  for(int o=32;o;o>>=1){ sp+=__shfl_down(sp,o); sa+=__shfl_down(sa,o); spa+=__shfl_down(spa,o); }
  if(lane==0){ pp[v]=sp; aa[v]=sqrtf(sa+EPSF); pa[v]=spa; }
}

// ---------------- embedding gather ----------------
__global__ void k_embed(const int* __restrict__ inp, const float* __restrict__ E, float* __restrict__ X){
  int n = blockIdx.x; int t = n >> 4, b = n & 15;
  int tok = inp[b*Ss + t];
  int i = threadIdx.x;
  st4(X + (size_t)n*Hh + i*4, ld4(E + (size_t)tok*Hh + i*4));
}

// ---------------- row logmap0 ----------------
__global__ void k_logmap(const float* __restrict__ X, float* __restrict__ LX){
  int n = blockIdx.x; int t = threadIdx.x;
  __shared__ float sred[2];
  float4 v = ld4(X + (size_t)n*Hh + t*4);
  float ss = dot4(v,v);
  for(int o=32;o;o>>=1) ss += __shfl_down(ss,o);
  if((t&63)==0) sred[t>>6] = ss;
  __syncthreads();
  ss = sred[0]+sred[1];
  float nn = sqrtf(ss + EPSF);
  float sc = atanhf(fminf(nn, MAXNRM)) / nn;
  v.x*=sc; v.y*=sc; v.z*=sc; v.w*=sc;
  st4(LX + (size_t)n*Hh + t*4, v);
}

// ---------------- row expmap0 (in place, 3 buffers) ----------------
__global__ void k_expmap(float* __restrict__ XR, float* __restrict__ XZ, float* __restrict__ XH){
  float* Xp = blockIdx.y==0 ? XR : (blockIdx.y==1 ? XZ : XH);
  int n = blockIdx.x; int t = threadIdx.x;
  __shared__ float sred[2];
  float4 v = ld4(Xp + (size_t)n*Hh + t*4);
  float ss = dot4(v,v);
  for(int o=32;o;o>>=1) ss += __shfl_down(ss,o);
  if((t&63)==0) sred[t>>6] = ss;
  __syncthreads();
  ss = sred[0]+sred[1];
  float nn = sqrtf(ss + EPSF);
  float sc = tanhf(nn) / nn;
  v.x*=sc; v.y*=sc; v.z*=sc; v.w*=sc;
  st4(Xp + (size_t)n*Hh + t*4, v);
}

// ---------------- GEMM for layer-0 inputs ----------------
__global__ __launch_bounds__(256) void k_gemm(const float* __restrict__ A4,
    const float* __restrict__ U0, const float* __restrict__ U1, const float* __restrict__ U2,
    float* __restrict__ O0, float* __restrict__ O1, float* __restrict__ O2){
  __shared__ float As[16][65], Bs[16][65];
  int jb = blockIdx.x;
  int nb = blockIdx.y;
  int mat = jb >> 3; int j0 = (jb & 7)*64;
  const float* Bm = mat==0?U0 : (mat==1?U1:U2);
  float* Om       = mat==0?O0 : (mat==1?O1:O2);
  int tid = threadIdx.x;
  int lr = tid >> 2, lq = tid & 3;
  int tx = tid & 15, ty = tid >> 4;
  float acc[4][4] = {};
  for(int kb=0; kb<Hh; kb+=16){
    float4 av = ld4(A4 + (size_t)(nb*64+lr)*Hh + kb + lq*4);
    float4 bv = ld4(Bm + (size_t)(j0+lr)*Hh + kb + lq*4);
    As[lq*4+0][lr]=av.x; As[lq*4+1][lr]=av.y; As[lq*4+2][lr]=av.z; As[lq*4+3][lr]=av.w;
    Bs[lq*4+0][lr]=bv.x; Bs[lq*4+1][lr]=bv.y; Bs[lq*4+2][lr]=bv.z; Bs[lq*4+3][lr]=bv.w;
    __syncthreads();
    #pragma unroll
    for(int kk=0;kk<16;kk++){
      float a0=As[kk][ty*4+0], a1=As[kk][ty*4+1], a2=As[kk][ty*4+2], a3=As[kk][ty*4+3];
      float b0=Bs[kk][tx*4+0], b1=Bs[kk][tx*4+1], b2=Bs[kk][tx*4+2], b3=Bs[kk][tx*4+3];
      acc[0][0]+=a0*b0; acc[0][1]+=a0*b1; acc[0][2]+=a0*b2; acc[0][3]+=a0*b3;
      acc[1][0]+=a1*b0; acc[1][1]+=a1*b1; acc[1][2]+=a1*b2; acc[1][3]+=a1*b3;
      acc[2][0]+=a2*b0; acc[2][1]+=a2*b1; acc[2][2]+=a2*b2; acc[2][3]+=a2*b3;
      acc[3][0]+=a3*b0; acc[3][1]+=a3*b1; acc[3][2]+=a3*b2; acc[3][3]+=a3*b3;
    }
    __syncthreads();
  }
  for(int i=0;i<4;i++)
    for(int j2=0;j2<4;j2++)
      Om[(size_t)(nb*64+ty*4+i)*Hh + j0 + tx*4 + j2] = acc[i][j2];
}

// ---------------- fused 3-layer pipelined GRU scan: chain-overlap consumer ----------------
__global__ __launch_bounds__(1024) void k_mega(
    const float* __restrict__ XR, const float* __restrict__ XZ, const float* __restrict__ XH,
    const float* __restrict__ pubX,
    const uint* __restrict__ W8, const uint* __restrict__ W8h,
    const uint* __restrict__ U8, const uint* __restrict__ U8h,
    const float* __restrict__ brA, const float* __restrict__ bzA, const float* __restrict__ bhA,
    uint* __restrict__ LH0, uint* __restrict__ LH1,
    int* __restrict__ flags0, int* __restrict__ flags1,
    float* __restrict__ Xfin){
  const int xcd = blockIdx.x & 7;
  const int layer = xcd >> 1;
  if(layer >= 3) return;
  const int b = (xcd & 1)*8 + (blockIdx.x >> 3);
  const int tid = threadIdx.x;
  const int lane = tid & 63, wv = tid >> 6;
  const int j8 = lane * 8;

  const uint* W8r = W8 + (size_t)(layer*2+0)*128*Hh;
  const uint* W8z = W8 + (size_t)(layer*2+1)*128*Hh;
  const uint* Wh8 = W8h + (size_t)layer*128*Hh;
  const uint* U8r = U8 + (size_t)(layer*2+0)*128*Hh;
  const uint* U8z = U8 + (size_t)(layer*2+1)*128*Hh;
  const uint* Uh8 = U8h + (size_t)layer*128*Hh;
  const float* br = brA + layer*Hh;
  const float* bz = bzA + layer*Hh;
  const float* bh = bhA + layer*Hh;
  uint* outLH = (layer==0)? LH0 : (layer==1)? LH1 : nullptr;
  int* outF = (layer==0)? flags0 : (layer==1)? flags1 : nullptr;
  const uint* inLH = (layer==1)? LH0 : LH1;
  int* inF = (layer==1)? flags0 : flags1;

  __shared__ float part[16][Hh];     // 32KB
  __shared__ float partC[8][Hh];     // 16KB (consumer Uh partials)
  __shared__ float mr_s[Hh], mur_s[Hh];
  __shared__ uint  lh2_s[256], ap2_s[256], lx2_s[256];
  __shared__ float bias0[Hh], bias1[Hh], bias2[Hh];
  __shared__ float partA[8][16];
  __shared__ float partB[8][18];
  __shared__ float coefA_s[12], coefB_s[8], bb_s[4];

  if(tid<256) lh2_s[tid]=0u;
  for(int i=tid;i<Hh;i+=1024){ bias0[i]=br[i]; bias1[i]=bz[i]; bias2[i]=bh[i]; }
  __syncthreads();
  {
    float p0=0,p1=0,p2=0;
    if(tid<Hh){ float a=bias0[tid],b2=bias1[tid],c2=bias2[tid]; p0=a*a; p1=b2*b2; p2=c2*c2; }
    p0=rsum64f(p0); p1=rsum64f(p1); p2=rsum64f(p2);
    if(tid<Hh && lane==0){ partB[wv][0]=p0; partB[wv][1]=p1; partB[wv][2]=p2; }
    __syncthreads();
    if(tid==0){
      float a=0,b2=0,c2=0;
      for(int i=0;i<8;i++){ a+=partB[i][0]; b2+=partB[i][1]; c2+=partB[i][2]; }
      bb_s[0]=a; bb_s[1]=b2; bb_s[2]=c2;
    }
    __syncthreads();
  }

  float h = 0.f;
  float Sh = 0.f, hxh = 0.f, hbh = 0.f;   // tid 0 (producer path)

  for(int ts=0; ts<Ss; ts++){
    const size_t row = (size_t)(ts*Bb + b)*Hh;
    const size_t lrow = (size_t)(ts*Bb + b)*256;

    if(layer == 0){
      // ======== producer (layer 0): verified body ========
      float xr=0,xz=0,xh=0;
      if(tid<512){ xr=XR[row+tid]; xz=XZ[row+tid]; xh=XH[row+tid]; }
      stream_e5m2_pair(W8r, W8z, lh2_s, part, tid, j8);
      __syncthreads();
      float mr=0.f, mz=0.f;
      if(tid<512){
        float s0=0, s1=0;
        #pragma unroll
        for(int q=0;q<8;q++){ s0+=part[q][tid]; s1+=part[8+q][tid]; }
        mr=s0; mz=s1; mr_s[tid]=s0;
        float brc=bias0[tid], bzc=bias1[tid], bhc=bias2[tid];
        float p0=mr*mr, p1=mr*xr, p2=mr*brc, p3=mz*mz, p4=mz*xz, p5=mz*bzc, p6=h*xh, p7=h*bhc;
        p0=rsum64f(p0); p1=rsum64f(p1); p2=rsum64f(p2); p3=rsum64f(p3);
        p4=rsum64f(p4); p5=rsum64f(p5); p6=rsum64f(p6); p7=rsum64f(p7);
        if(lane==0){
          partA[wv][0]=p0; partA[wv][1]=p1; partA[wv][2]=p2; partA[wv][3]=p3;
          partA[wv][4]=p4; partA[wv][5]=p5; partA[wv][6]=p6; partA[wv][7]=p7;
        }
      }
      __syncthreads();
      if(tid==0){
        float s[8];
        #pragma unroll
        for(int d=0;d<8;d++){
          float x=0;
          for(int i=0;i<8;i++) x+=partA[i][d];
          s[d]=x;
        }
        hxh=s[6]; hbh=s[7];
        const float* px = pubX + (size_t)(ts*Bb+b)*6;
        float xrxr=px[0], xrbr=px[1], xzxz=px[2], xzbz=px[3];
        float bbr=bb_s[0], bbz=bb_s[1];
        float nm=sqrtf(s[0]+EPSF), se=tanhf(nm)/nm;
        float uv=se*s[1], uu=se*se*s[0];
        float den=1.f+2.f*uv+uu*xrxr;
        float a1=(1.f+2.f*uv+xrxr)*se/den, a2=(1.f-uu)/den;
        float uv2=a1*s[2]+a2*xrbr;
        float uu2=a1*a1*s[0]+2.f*a1*a2*s[1]+a2*a2*xrxr;
        float den2=1.f+2.f*uv2+uu2*bbr;
        float b1=(1.f+2.f*uv2+bbr)/den2, b2c=(1.f-uu2)/den2;
        float c1=b1*a1, c2=b1*a2, c3=b2c;
        float n2sq=c1*c1*s[0]+c2*c2*xrxr+c3*c3*bbr+2.f*(c1*c2*s[1]+c1*c3*s[2]+c2*c3*xrbr);
        float nn2=sqrtf(n2sq+EPSF);
        float s_r=atanhf(fminf(nn2,MAXNRM))/nn2;
        coefA_s[0]=s_r*c1; coefA_s[1]=s_r*c2; coefA_s[2]=s_r*c3;
        float nmz=sqrtf(s[3]+EPSF), sez=tanhf(nmz)/nmz;
        float uvz=sez*s[4], uuz=sez*sez*s[3];
        float denz=1.f+2.f*uvz+uuz*xzxz;
        float az1=(1.f+2.f*uvz+xzxz)*sez/denz, az2=(1.f-uuz)/denz;
        float uvz2=az1*s[5]+az2*xzbz;
        float uuz2=az1*az1*s[3]+2.f*az1*az2*s[4]+az2*az2*xzxz;
        float denz2=1.f+2.f*uvz2+uuz2*bbz;
        float bz1=(1.f+2.f*uvz2+bbz)/denz2, bz2=(1.f-uuz2)/denz2;
        float cz1=bz1*az1, cz2=bz1*az2, cz3=bz2;
        float nz2sq=cz1*cz1*s[3]+cz2*cz2*xzxz+cz3*cz3*bbz+2.f*(cz1*cz2*s[4]+cz1*cz3*s[5]+cz2*cz3*xzbz);
        float nnz2=sqrtf(nz2sq+EPSF);
        float s_z=atanhf(fminf(nnz2,MAXNRM))/nnz2;
        coefA_s[3]=s_z*cz1; coefA_s[4]=s_z*cz2; coefA_s[5]=s_z*cz3;
        coefA_s[6]=px[4]; coefA_s[7]=px[4]; coefA_s[8]=px[5];
      }
      __syncthreads();
      if(tid<256){
        int e0 = tid*2;
        float ca=coefA_s[0], cb=coefA_s[1], cc2=coefA_s[2];
        h2 lp = __builtin_bit_cast(h2, lh2_s[tid]);
        float r0 = sigm(ca*mr_s[e0]   + cb*XR[row+e0]   + cc2*bias0[e0]);
        float r1 = sigm(ca*mr_s[e0+1] + cb*XR[row+e0+1] + cc2*bias0[e0+1]);
        ap2_s[tid] = (uint)f2h(r0*(float)lp[0]) | ((uint)f2h(r1*(float)lp[1])<<16);
      }
      __syncthreads();
      stream_e5m2_rows<8,16>(Wh8, ap2_s, part, (tid>>6)*8, lane, tid>>6);
      __syncthreads();
      float mh=0.f, z=0.f;
      if(tid<512){
        float s=0;
        #pragma unroll
        for(int q=0;q<16;q++) s+=part[q][tid];
        mh=s;
        float bhc=bias2[tid], bzc=bias1[tid];
        z = sigm(coefA_s[3]*mz + coefA_s[4]*xz + coefA_s[5]*bzc);
        float eh=z*h, em=z*mh, ex=z*xh, eb=z*bhc;
        float p[18] = {mh*mh, mh*xh, mh*bhc, h*mh,
                       eh*eh, eh*em, eh*ex, eh*eb,
                       em*em, em*ex, em*eb, ex*ex, ex*eb, eb*eb,
                       h*eh, h*em, h*ex, h*eb};
        #pragma unroll
        for(int d=0;d<18;d++) p[d]=rsum64f(p[d]);
        if(lane==0){
          #pragma unroll
          for(int d=0;d<18;d++) partB[wv][d]=p[d];
        }
      }
      __syncthreads();
      if(tid==0){
        float dsum[18];
        #pragma unroll
        for(int d=0;d<18;d++){
          float x=0;
          for(int i=0;i<8;i++) x+=partB[i][d];
          dsum[d]=x;
        }
        float d0=dsum[0], d1=dsum[1], d2=dsum[2], d3=dsum[3];
        float Ghh=dsum[4], Ghm=dsum[5], Ghx=dsum[6], Ghb=dsum[7];
        float Gmm=dsum[8], Gmx=dsum[9], Gmb=dsum[10];
        float Gxx=dsum[11], Gxb=dsum[12], Gbb=dsum[13];
        float Heh=dsum[14], Hem=dsum[15], Hex=dsum[16], Heb=dsum[17];
        float xhxh=coefA_s[7], xhbh=coefA_s[8];
        float bbh=bb_s[2]; float Shb=Sh;
        float nm3=sqrtf(d0+EPSF), se3=tanhf(nm3)/nm3;
        float uvh=se3*d1, uuh=se3*se3*d0;
        float denh=1.f+2.f*uvh+uuh*xhxh;
        float a1p=(1.f+2.f*uvh+xhxh)*se3/denh, a2p=(1.f-uuh)/denh;
        float uv2h=a1p*d2+a2p*xhbh;
        float uu2h=a1p*a1p*d0+2.f*a1p*a2p*d1+a2p*a2p*xhxh;
        float den2h=1.f+2.f*uv2h+uu2h*bbh;
        float b1p=(1.f+2.f*uv2h+bbh)/den2h, b2p=(1.f-uu2h)/den2h;
        float c1p=b1p*a1p, c2p=b1p*a2p, c3p=b2p;
        float h_htil=c1p*d3+c2p*hxh+c3p*hbh;
        float htil2=c1p*c1p*d0+c2p*c2p*xhxh+c3p*c3p*bbh
                  +2.f*(c1p*c2p*d1+c1p*c3p*d2+c2p*c3p*xhbh);
        float denD=1.f-2.f*h_htil+Shb*htil2;
        float dd1=(1.f-2.f*h_htil+htil2)/denD, dd2=(1.f-Shb)/denD;
        float g0=-dd1, g1=dd2*c1p, g2=dd2*c2p, g3=dd2*c3p;
        float del2=g0*g0*Shb+g1*g1*d0+g2*g2*xhxh+g3*g3*bbh
                 +2.f*(g0*g1*d3+g0*g2*hxh+g0*g3*hbh+g1*g2*d1+g1*g3*d2+g2*g3*xhbh);
        float ndl=sqrtf(del2+EPSF);
        float sld=atanhf(fminf(ndl,MAXNRM))/ndl;
        float Qe=g0*g0*Ghh+g1*g1*Gmm+g2*g2*Gxx+g3*g3*Gbb
               +2.f*(g0*g1*Ghm+g0*g2*Ghx+g0*g3*Ghb+g1*g2*Gmx+g1*g3*Gmb+g2*g3*Gxb);
        float Le=g0*Heh+g1*Hem+g2*Hex+g3*Heb;
        float Sww=sld*sld*Qe;
        float Shw=sld*Le;
        float nw=sqrtf(Sww+EPSF), sew=tanhf(nw)/nw;
        float uvw=sew*Shw, vvw=sew*sew*Sww;
        float denw=1.f+2.f*uvw+Shb*vvw;
        float q1=(1.f+2.f*uvw+vvw)/denw, q2=((1.f-Shb)/denw)*sew;
        float n2h=q1*q1*Shb+2.f*q1*q2*Shw+q2*q2*Sww;
        float nrm=sqrtf(n2h+EPSF);
        float scl=fminf(1.f, MAXNRM/nrm);
        float Shn=scl*scl*n2h;
        float nh2=sqrtf(Shn+EPSF);
        float slh=atanhf(fminf(nh2,MAXNRM))/nh2;
        coefB_s[0]=scl*q1; coefB_s[1]=scl*q2*sld;
        coefB_s[2]=g0; coefB_s[3]=g1; coefB_s[4]=g2; coefB_s[5]=g3;
        coefB_s[6]=slh;
        Sh=Shn;
      }
      __syncthreads();
      if(tid<512){
        float qc1=coefB_s[0], qc2=coefB_s[1];
        float g0=coefB_s[2], g1=coefB_s[3], g2=coefB_s[4], g3=coefB_s[5];
        float slh=coefB_s[6];
        float dl = g0*h + g1*mh + g2*xh + g3*bias2[tid];
        float hn = qc1*h + qc2*z*dl;
        h = hn;
        float lh = slh*hn;
        float lhp = __shfl_xor(lh, 1);
        if(!(tid&1)){
          uint pk = (uint)f2h(lh) | ((uint)f2h(lhp)<<16);
          lh2_s[tid>>1] = pk;
          stg_scu(outLH + lrow + (tid>>1), pk);
        }
      }
      __syncthreads();
      if(tid==0) __hip_atomic_store(outF + b*Ss + ts, 1, __ATOMIC_RELAXED, __HIP_MEMORY_SCOPE_AGENT);
    } else {
      // ======== consumer (layers 1,2): merged-stream + chain-overlap, 8 barriers ========
      if(tid < 512){
        if(wv < 4) stream_e5m2_rows<32,16>(W8r, lh2_s, part, wv*32, lane, wv);
        else       stream_e5m2_rows<32,16>(W8z, lh2_s, part, (wv-4)*32, lane, wv);
      } else {
        int uw = wv - 8;              // 0..7
        int rbase = (uw & 3) * 32;    // k4-row base (0,32,64,96)
        if(lane==0){
          while(__hip_atomic_load(inF + b*Ss + ts, __ATOMIC_RELAXED, __HIP_MEMORY_SCOPE_AGENT) == 0)
            __builtin_amdgcn_s_sleep(1);
        }
        lx2_s[rbase*2 + lane] = ldg_scu(inLH + lrow + rbase*2 + lane);
        if(uw < 4) stream_e5m2_rows<32,16>(U8r, lx2_s, part, rbase, lane, wv);
        else       stream_e5m2_rows<32,16>(U8z, lx2_s, part, rbase, lane, wv);
      }
      __syncthreads();   // B1

      float mr=0.f, mz=0.f, mur=0.f, muz=0.f;
      if(tid < 512){
        mr  = part[0][tid]+part[1][tid]+part[2][tid]+part[3][tid];
        mz  = part[4][tid]+part[5][tid]+part[6][tid]+part[7][tid];
        mur = part[8][tid]+part[9][tid]+part[10][tid]+part[11][tid];
        muz = part[12][tid]+part[13][tid]+part[14][tid]+part[15][tid];
        mr_s[tid]=mr; mur_s[tid]=mur;
        float brc=bias0[tid], bzc=bias1[tid];
        float p0=mr*mr, p1=mr*brc, p2=mz*mz, p3=mz*bzc;
        float p5=mur*mur, p6=mur*brc, p7=muz*muz, p8=muz*bzc, p9=mr*mur, p10=mz*muz;
        p0=rsum64f(p0); p1=rsum64f(p1); p2=rsum64f(p2); p3=rsum64f(p3);
        p5=rsum64f(p5); p6=rsum64f(p6); p7=rsum64f(p7);
        p8=rsum64f(p8); p9=rsum64f(p9); p10=rsum64f(p10);
        if(lane==0){
          partA[wv][0]=p0; partA[wv][1]=p1; partA[wv][2]=p2; partA[wv][3]=p3;
          partA[wv][5]=p5; partA[wv][6]=p6; partA[wv][7]=p7;
          partA[wv][8]=p8; partA[wv][9]=p9; partA[wv][10]=p10;
        }
      } else {
        stream_e5m2_rows<16,8>(Uh8, lx2_s, partC, (wv-8)*16, lane, wv-8);
      }
      __syncthreads();   // B2

      float muh=0.f;
      if(tid<512){
        float s=0;
        #pragma unroll
        for(int q=0;q<8;q++) s+=partC[q][tid];
        muh=s;
        float bhc=bias2[tid];
        float p11=muh*muh, p12=h*muh, p13=muh*bhc, p14=h*bhc;
        p11=rsum64f(p11); p12=rsum64f(p12); p13=rsum64f(p13); p14=rsum64f(p14);
        if(lane==0){ partA[wv][11]=p11; partA[wv][12]=p12; partA[wv][13]=p13; partA[wv][14]=p14; }
      } else if(tid==512){
        float S[11];
        #pragma unroll
        for(int d=0;d<11;d++){
          float xS=0;
          for(int i=0;i<8;i++) xS+=partA[i][d];
          S[d]=xS;
        }
        float bbr=bb_s[0], bbz=bb_s[1];
        float nur=sqrtf(S[5]+EPSF), se_r=tanhf(nur)/nur;
        float nuz=sqrtf(S[7]+EPSF), se_z=tanhf(nuz)/nuz;
        float s0=S[0], s1=se_r*S[9], s2=S[1];
        float xrxr=se_r*se_r*S[5], xrbr=se_r*S[6];
        float s3=S[2], s4=se_z*S[10], s5=S[3];
        float xzxz=se_z*se_z*S[7], xzbz=se_z*S[8];
        float nm=sqrtf(s0+EPSF), se=tanhf(nm)/nm;
        float uv=se*s1, uu=se*se*s0;
        float den=1.f+2.f*uv+uu*xrxr;
        float a1=(1.f+2.f*uv+xrxr)*se/den, a2=(1.f-uu)/den;
        float uv2=a1*s2+a2*xrbr;
        float uu2=a1*a1*s0+2.f*a1*a2*s1+a2*a2*xrxr;
        float den2=1.f+2.f*uv2+uu2*bbr;
        float b1=(1.f+2.f*uv2+bbr)/den2, b2c=(1.f-uu2)/den2;
        float c1=b1*a1, c2=b1*a2, c3=b2c;
        float n2sq=c1*c1*s0+c2*c2*xrxr+c3*c3*bbr+2.f*(c1*c2*s1+c1*c3*s2+c2*c3*xrbr);
        float nn2=sqrtf(n2sq+EPSF);
        float s_r=atanhf(fminf(nn2,MAXNRM))/nn2;
        coefA_s[0]=s_r*c1; coefA_s[1]=s_r*c2*se_r; coefA_s[2]=s_r*c3;
        float nmz=sqrtf(s3+EPSF), sez=tanhf(nmz)/nmz;
        float uvz=sez*s4, uuz=sez*sez*s3;
        float denz=1.f+2.f*uvz+uuz*xzxz;
        float az1=(1.f+2.f*uvz+xzxz)*sez/denz, az2=(1.f-uuz)/denz;
        float uvz2=az1*s5+az2*xzbz;
        float uuz2=az1*az1*s3+2.f*az1*az2*s4+az2*az2*xzxz;
        float denz2=1.f+2.f*uvz2+uuz2*bbz;
        float bz1=(1.f+2.f*uvz2+bbz)/denz2, bz2=(1.f-uuz2)/denz2;
        float cz1=bz1*az1, cz2=bz1*az2, cz3=bz2;
        float nz2sq=cz1*cz1*s3+cz2*cz2*xzxz+cz3*cz3*bbz+2.f*(cz1*cz2*s4+cz1*cz3*s5+cz2*cz3*xzbz);
        float nnz2=sqrtf(nz2sq+EPSF);
        float s_z=atanhf(fminf(nnz2,MAXNRM))/nnz2;
        coefA_s[3]=s_z*cz1; coefA_s[4]=s_z*cz2*se_z; coefA_s[5]=s_z*cz3;
      }
      __syncthreads();   // B3

      if(tid<256){
        int e0 = tid*2;
        float ca=coefA_s[0], cbp=coefA_s[1], cc2=coefA_s[2];
        h2 lp = __builtin_bit_cast(h2, lh2_s[tid]);
        float r0 = sigm(ca*mr_s[e0]   + cbp*mur_s[e0]   + cc2*bias0[e0]);
        float r1 = sigm(ca*mr_s[e0+1] + cbp*mur_s[e0+1] + cc2*bias0[e0+1]);
        ap2_s[tid] = (uint)f2h(r0*(float)lp[0]) | ((uint)f2h(r1*(float)lp[1])<<16);
      } else if(tid==512){
        float S11=0,S12=0,S13=0,S14=0;
        #pragma unroll
        for(int i=0;i<8;i++){
          S11+=partA[i][11]; S12+=partA[i][12]; S13+=partA[i][13]; S14+=partA[i][14];
        }
        float nuh=sqrtf(S11+EPSF), se_h=tanhf(nuh)/nuh;
        coefA_s[6]=se_h;
        coefA_s[7]=se_h*se_h*S11;   // xhxh
        coefA_s[8]=se_h*S13;        // xhbh
        coefA_s[9]=se_h*S12;        // hxh
        coefA_s[10]=S14;            // hbh
      }
      __syncthreads();   // B4

      stream_e5m2_rows<8,16>(Wh8, ap2_s, part, (tid>>6)*8, lane, tid>>6);
      __syncthreads();   // B5

      float mh=0.f, z=0.f;
      if(tid<512){
        float s=0;
        #pragma unroll
        for(int q=0;q<16;q++) s+=part[q][tid];
        mh=s;
        float se_h = coefA_s[6];
        float xh = se_h*muh;
        float bhc=bias2[tid], bzc=bias1[tid];
        z = sigm(coefA_s[3]*mz + coefA_s[4]*muz + coefA_s[5]*bzc);
        float eh=z*h, em=z*mh, ex=z*xh, eb=z*bhc;
        float p[18] = {mh*mh, mh*xh, mh*bhc, h*mh,
                       eh*eh, eh*em, eh*ex, eh*eb,
                       em*em, em*ex, em*eb, ex*ex, ex*eb, eb*eb,
                       h*eh, h*em, h*ex, h*eb};
        #pragma unroll
        for(int d=0;d<18;d++) p[d]=rsum64f(p[d]);
        if(lane==0){
          #pragma unroll
          for(int d=0;d<18;d++) partB[wv][d]=p[d];
        }
      }
      __syncthreads();   // B6

      if(tid==0){
        float dsum[18];
        #pragma unroll
        for(int d=0;d<18;d++){
          float xS=0;
          for(int i=0;i<8;i++) xS+=partB[i][d];
          dsum[d]=xS;
        }
        float d0=dsum[0], d1=dsum[1], d2=dsum[2], d3=dsum[3];
        float Ghh=dsum[4], Ghm=dsum[5], Ghx=dsum[6], Ghb=dsum[7];
        float Gmm=dsum[8], Gmx=dsum[9], Gmb=dsum[10];
        float Gxx=dsum[11], Gxb=dsum[12], Gbb=dsum[13];
        float Heh=dsum[14], Hem=dsum[15], Hex=dsum[16], Heb=dsum[17];
        float xhxh=coefA_s[7], xhbh=coefA_s[8];
        float hxhv=coefA_s[9], hbhv=coefA_s[10];
        float bbh=bb_s[2]; float Shb=Sh;
        float nm3=sqrtf(d0+EPSF), se3=tanhf(nm3)/nm3;
        float uvh=se3*d1, uuh=se3*se3*d0;
        float denh=1.f+2.f*uvh+uuh*xhxh;
        float a1p=(1.f+2.f*uvh+xhxh)*se3/denh, a2p=(1.f-uuh)/denh;
        float uv2h=a1p*d2+a2p*xhbh;
        float uu2h=a1p*a1p*d0+2.f*a1p*a2p*d1+a2p*a2p*xhxh;
        float den2h=1.f+2.f*uv2h+uu2h*bbh;
        float b1p=(1.f+2.f*uv2h+bbh)/den2h, b2p=(1.f-uu2h)/den2h;
        float c1p=b1p*a1p, c2p=b1p*a2p, c3p=b2p;
        float h_htil=c1p*d3+c2p*hxhv+c3p*hbhv;
        float htil2=c1p*c1p*d0+c2p*c2p*xhxh+c3p*c3p*bbh
                  +2.f*(c1p*c2p*d1+c1p*c3p*d2+c2p*c3p*xhbh);
        float denD=1.f-2.f*h_htil+Shb*htil2;
        float dd1=(1.f-2.f*h_htil+htil2)/denD, dd2=(1.f-Shb)/denD;
        float g0=-dd1, g1=dd2*c1p, g2=dd2*c2p, g3=dd2*c3p;
        float del2=g0*g0*Shb+g1*g1*d0+g2*g2*xhxh+g3*g3*bbh
                 +2.f*(g0*g1*d3+g0*g2*hxhv+g0*g3*hbhv+g1*g2*d1+g1*g3*d2+g2*g3*xhbh);
        float ndl=sqrtf(del2+EPSF);
        float sld=atanhf(fminf(ndl,MAXNRM))/ndl;
        float Qe=g0*g0*Ghh+g1*g1*Gmm+g2*g2*Gxx+g3*g3*Gbb
               +2.f*(g0*g1*Ghm+g0*g2*Ghx+g0*g3*Ghb+g1*g2*Gmx+g1*g3*Gmb+g2*g3*Gxb);
        float Le=g0*Heh+g1*Hem+g2*Hex+g3*Heb;
        float Sww=sld*sld*Qe;
        float Shw=sld*Le;
        float nw=sqrtf(Sww+EPSF), sew=tanhf(nw)/nw;
        float uvw=sew*Shw, vvw=sew*sew*Sww;
        float denw=1.f+2.f*uvw+Shb*vvw;
        float q1=(1.f+2.f*uvw+vvw)/denw, q2=((1.f-Shb)/denw)*sew;
        float n2h=q1*q1*Shb+2.f*q1*q2*Shw+q2*q2*Sww;
        float nrm=sqrtf(n2h+EPSF);
        float scl=fminf(1.f, MAXNRM/nrm);
        float Shn=scl*scl*n2h;
        float nh2=sqrtf(Shn+EPSF);
        float slh=atanhf(fminf(nh2,MAXNRM))/nh2;
        coefB_s[0]=scl*q1; coefB_s[1]=scl*q2*sld;
        coefB_s[2]=g0; coefB_s[3]=g1; coefB_s[4]=g2; coefB_s[5]=g3;
        coefB_s[6]=slh;
        Sh=Shn;
      }
      __syncthreads();   // B7

      if(tid<512){
        float qc1=coefB_s[0], qc2=coefB_s[1];
        float g0=coefB_s[2], g1=coefB_s[3], g2=coefB_s[4], g3=coefB_s[5];
        float slh=coefB_s[6];
        float xh = coefA_s[6]*muh;
        float dl = g0*h + g1*mh + g2*xh + g3*bias2[tid];
        float hn = qc1*h + qc2*z*dl;
        h = hn;
        if(layer==2) Xfin[row + tid] = hn;
        float lh = slh*hn;
        float lhp = __shfl_xor(lh, 1);
        if(!(tid&1)){
          uint pk = (uint)f2h(lh) | ((uint)f2h(lhp)<<16);
          lh2_s[tid>>1] = pk;
          if(layer==1) stg_scu(outLH + lrow + (tid>>1), pk);
        }
      }
      __syncthreads();   // B8
      if(layer==1 && tid==0)
        __hip_atomic_store(outF + b*Ss + ts, 1, __ATOMIC_RELAXED, __HIP_MEMORY_SCOPE_AGENT);
    }
  }
}

// ---------------- pack 16 rows of a [*,512] f32 matrix into bf16 MFMA fragments ----------------
__global__ __launch_bounds__(256) void k_packF(const float* __restrict__ src, ushort* __restrict__ dst){
  int vt = blockIdx.x;
  __shared__ float rows[16][516];
  int tid = threadIdx.x;
  #pragma unroll
  for(int p=0;p<8;p++){
    int idx = p*256 + tid;
    int row = idx >> 7, c4 = idx & 127;
    st4(&rows[row][c4*4], ld4(src + ((size_t)vt*16+row)*Hh + c4*4));
  }
  __syncthreads();
  #pragma unroll
  for(int p=0;p<4;p++){
    int idx = p*256 + tid;
    int kt = idx >> 6, lane = idx & 63;
    int vloc = lane & 15, k0 = kt*32 + ((lane>>4)&3)*8;
    union { ushort u[8]; uint4 v; } tt;
    #pragma unroll
    for(int i=0;i<8;i++) tt.u[i] = f2bf(rows[vloc][k0+i]);
    *(uint4*)(dst + (((size_t)vt*16 + kt)*64 + lane)*8) = tt.v;
  }
}

// ---------------- MFMA MLR + online softmax partials ----------------
__global__ __launch_bounds__(256) void k_mlr2(
    const ushort* __restrict__ Xf, const ushort* __restrict__ Pf, const ushort* __restrict__ Af,
    const float* __restrict__ X, const float* __restrict__ pp, const float* __restrict__ aa,
    const float* __restrict__ pa, const int* __restrict__ tgt,
    float* __restrict__ pm, float* __restrict__ tl){
  int rb = blockIdx.x;
  int sp = blockIdx.y;
  int tid = threadIdx.x, lane = tid&63, w = tid>>6;
  __shared__ ushort Axf[4*16*64*8];
  __shared__ float xxp[64][4];
  __shared__ float xxs[64];
  #pragma unroll
  for(int p=0;p<16;p++){
    int idx = p*256 + tid;
    ((uint4*)Axf)[idx] = ((const uint4*)Xf)[(size_t)rb*4096 + idx];
  }
  {
    int row = tid>>2, seg = tid&3;
    const float* xr = X + ((size_t)rb*64 + row)*Hh + seg*128;
    float s=0;
    #pragma unroll
    for(int i=0;i<32;i++){ float4 v4 = ld4(xr+i*4); s += dot4(v4,v4); }
    xxp[row][seg]=s;
  }
  __syncthreads();
  if(tid<64) xxs[tid] = xxp[tid][0]+xxp[tid][1]+xxp[tid][2]+xxp[tid][3];
  __syncthreads();

  float mM[16], sS[16]; int tokv[16];
  #pragma unroll
  for(int rt=0;rt<4;rt++)
    #pragma unroll
    for(int i=0;i<4;i++){
      int idx=rt*4+i;
      int rr = rb*64 + rt*16 + (lane>>4)*4 + i;
      tokv[idx] = tgt[(rr&15)*Ss + (rr>>4)];
      mM[idx] = -3.0e38f; sS[idx]=0.f;
    }

  for(int vt = sp*4 + w; vt < VT; vt += 32){
    int v = vt*16 + (lane&15);
    float ppv = pp[v], aav = aa[v], pav = pa[v];
    f32x4 aP[4], aA[4];
    #pragma unroll
    for(int rt=0;rt<4;rt++){ aP[rt]=(f32x4){0,0,0,0}; aA[rt]=(f32x4){0,0,0,0}; }
    const short8v* Pb = (const short8v*)(Pf + (size_t)vt*8192);
    const short8v* Ab = (const short8v*)(Af + (size_t)vt*8192);
    #pragma unroll
    for(int kt=0;kt<16;kt++){
      short8v bP = Pb[kt*64+lane];
      short8v bA = Ab[kt*64+lane];
      #pragma unroll
      for(int rt=0;rt<4;rt++){
        short8v a = *(const short8v*)&Axf[(((size_t)rt*16+kt)*64+lane)*8];
        aP[rt] = __builtin_amdgcn_mfma_f32_16x16x32_bf16(a, bP, aP[rt], 0,0,0);
        aA[rt] = __builtin_amdgcn_mfma_f32_16x16x32_bf16(a, bA, aA[rt], 0,0,0);
      }
    }
    float be = 1.f - ppv;
    float lamaa = (2.f/be)*aav;
    #pragma unroll
    for(int rt=0;rt<4;rt++)
      #pragma unroll
      for(int i=0;i<4;i++){
        int idx = rt*4+i;
        int rl = rt*16 + (lane>>4)*4 + i;
        float px = aP[rt][i], xa = aA[rt][i];
        float xx = xxs[rl];
        float al = 1.f - 2.f*px + xx;
        float gm = 1.f - 2.f*px + ppv*xx;
        float da = (-al*pav + be*xa)/gm;
        float dd = (al*al*ppv - 2.f*al*be*px + be*be*xx)/(gm*gm);
        float arg = 2.f*da/((1.f-dd)*aav + EPSF);
        float lg = lamaa*asinhf(arg);
        if(v == tokv[idx]) tl[rb*64 + rl] = lg;
        if(lg > mM[idx]){ sS[idx] = sS[idx]*expf(mM[idx]-lg) + 1.f; mM[idx]=lg; }
        else sS[idx] += expf(lg - mM[idx]);
      }
  }
  #pragma unroll
  for(int o=1;o<16;o<<=1){
    #pragma unroll
    for(int idx=0;idx<16;idx++){
      float m2 = __shfl_xor(mM[idx], o);
      float s2 = __shfl_xor(sS[idx], o);
      float M = fmaxf(mM[idx], m2);
      sS[idx] = sS[idx]*expf(mM[idx]-M) + s2*expf(m2-M);
      mM[idx] = M;
    }
  }
  if((lane&15)==0){
    #pragma unroll
    for(int rt=0;rt<4;rt++)
      #pragma unroll
      for(int i=0;i<4;i++){
        int idx=rt*4+i;
        int rr = rb*64 + rt*16 + (lane>>4)*4 + i;
        pm[((size_t)rr*32 + sp*4 + w)*2+0] = mM[idx];
        pm[((size_t)rr*32 + sp*4 + w)*2+1] = sS[idx];
      }
  }
}

// ---------------- final merge + mean NLL ----------------
__global__ void k_final(const float* __restrict__ pm, const float* __restrict__ tl, float* __restrict__ out){
  int tid = threadIdx.x;
  __shared__ float sred[4];
  float acc = 0.f;
  for(int q=0;q<8;q++){
    int rr = q*256 + tid;
    float M = -3.0e38f;
    for(int s=0;s<32;s++) M = fmaxf(M, pm[((size_t)rr*32+s)*2]);
    float Ssum = 0.f;
    for(int s=0;s<32;s++) Ssum += pm[((size_t)rr*32+s)*2+1]*expf(pm[((size_t)rr*32+s)*2]-M);
    acc += (M + logf(Ssum)) - tl[rr];
  }
  for(int o=32;o;o>>=1) acc += __shfl_down(acc,o);
  if((tid&63)==0) sred[tid>>6] = acc;
  __syncthreads();
  if(tid==0) out[0] = (sred[0]+sred[1]+sred[2]+sred[3]) / 2048.f;
}

extern "C" void kernel_launch(void* const* d_in, const int* in_sizes, int n_in,
                              void* d_out, int out_size, void* d_ws, size_t ws_size,
                              hipStream_t stream){
  const int* inp = (const int*)d_in[0];
  const int* tgt = (const int*)d_in[1];
  const float* E  = (const float*)d_in[2];
  const float* Wr = (const float*)d_in[3];
  const float* Wz = (const float*)d_in[4];
  const float* Wh = (const float*)d_in[5];
  const float* Ur = (const float*)d_in[6];
  const float* Uz = (const float*)d_in[7];
  const float* Uh = (const float*)d_in[8];
  const float* br = (const float*)d_in[9];
  const float* bz = (const float*)d_in[10];
  const float* bh = (const float*)d_in[11];
  const float* P  = (const float*)d_in[12];
  const float* A  = (const float*)d_in[13];
  float* out = (float*)d_out;
  float* w = (float*)d_ws;
  size_t o = 0;
  auto take = [&](size_t n){ float* p = w + o; o += n; return p; };
  float* Xa  = take((size_t)Nn*Hh);
  float* Xb  = take((size_t)Nn*Hh);
  float* LX  = take((size_t)Nn*Hh);
  float* XR  = take((size_t)Nn*Hh);
  float* XZ  = take((size_t)Nn*Hh);
  float* XH  = take((size_t)Nn*Hh);
  uint*  LH0 = (uint*)take((size_t)Nn*256);
  uint*  LH1 = (uint*)take((size_t)Nn*256);
  uint*  W8h = (uint*)take((size_t)3*128*Hh);
  uint*  W8  = (uint*)take((size_t)6*128*Hh);
  uint*  U8h = (uint*)take((size_t)3*128*Hh);
  uint*  U8  = (uint*)take((size_t)6*128*Hh);
  float* pubX = take((size_t)Nn*6);
  float* pp  = take(10240);
  float* aa  = take(10240);
  float* pa  = take(10240);
  float* pm  = take((size_t)Nn*32*2);
  float* tl  = take((size_t)Nn);
  int* flags = (int*)take(2*(size_t)Bb*Ss);
  if(ws_size < o*sizeof(float)) return;
  int* flags0 = flags;
  int* flags1 = flags + Bb*Ss;

  hipLaunchKernelGGL(k_packW8s, dim3(8,8,3), dim3(256), 0, stream, Wh, W8h);
  hipLaunchKernelGGL(k_packW8s, dim3(8,8,3), dim3(256), 0, stream, Uh, U8h);
  hipLaunchKernelGGL(k_packW8, dim3(8,8,6), dim3(256), 0, stream, Wr, Wz, W8);
  hipLaunchKernelGGL(k_packW8, dim3(8,8,6), dim3(256), 0, stream, Ur, Uz, U8);
  hipLaunchKernelGGL(k_pav, dim3(2500), dim3(256), 0, stream, P,A, pp,aa,pa);
  hipLaunchKernelGGL(k_embed, dim3(Nn), dim3(128), 0, stream, inp, E, Xa);
  hipLaunchKernelGGL(k_logmap, dim3(Nn), dim3(128), 0, stream, Xa, LX);
  hipLaunchKernelGGL(k_gemm, dim3(24,32), dim3(256), 0, stream, LX,
                     Ur, Uz, Uh, XR, XZ, XH);
  hipLaunchKernelGGL(k_expmap, dim3(Nn,3), dim3(128), 0, stream, XR,XZ,XH);
  hipLaunchKernelGGL(k_predots, dim3(Nn), dim3(128), 0, stream, XR,XZ,XH, br, bz, bh, pubX);
  hipMemsetAsync(flags, 0, 2*(size_t)Bb*Ss*sizeof(int), stream);
  hipLaunchKernelGGL(k_mega, dim3(64), dim3(1024), 0, stream,
                     XR,XZ,XH, pubX, W8,W8h,U8,U8h, br,bz,bh,
                     LH0, LH1, flags0, flags1, Xb);
  ushort* Pf = (ushort*)LX;
  ushort* Af = Pf + (size_t)VT*16*64*8;
  ushort* Xf = (ushort*)Xa;
  hipLaunchKernelGGL(k_packF, dim3(VT), dim3(256), 0, stream, P, Pf);
  hipLaunchKernelGGL(k_packF, dim3(VT), dim3(256), 0, stream, A, Af);
  hipLaunchKernelGGL(k_packF, dim3(128), dim3(256), 0, stream, Xb, Xf);
  hipLaunchKernelGGL(k_mlr2, dim3(32,8), dim3(256), 0, stream, Xf, Pf, Af, Xb,
                     pp, aa, pa, tgt, pm, tl);
  hipLaunchKernelGGL(k_final, dim3(1), dim3(256), 0, stream, pm, tl, out);
}